// Round 15
// baseline (5689.540 us; speedup 1.0000x reference)
//
#include <hip/hip_runtime.h>
#include <math.h>

#define S_ANCH 1024
#define B_QRY  2048
#define N_TOT  3072
#define D_DIM  1352
#define D_PAD  1408   // padded D: u16/psi stride, c16T rows
#define D_K    1376   // GEMM2 K extent (covers D_DIM, multiple of 32)
#define F_NUM  10
#define N_TV   19
#define NPART  44     // 22 n-tiles * 2 wave-halves in GEMM1
#define NB_EV  512    // fused eval kernel grid (guaranteed co-resident: 2/CU worst case)

static const size_t SD    = (size_t)S_ANCH * D_DIM;
static const size_t NS    = (size_t)N_TOT * S_ANCH;
static const size_t CST   = (size_t)D_PAD * S_ANCH;   // one c16T plane
static const size_t PSIP  = (size_t)N_TOT * D_PAD;    // one psi plane
static const size_t OUT_Z = (size_t)B_QRY * F_NUM * S_ANCH;

typedef __attribute__((ext_vector_type(8))) short bf16x8;
typedef __attribute__((ext_vector_type(4))) float f32x4;

struct W190 { float w[N_TV][F_NUM]; };

__device__ inline unsigned short f2bf(float x) {
    unsigned int u = __builtin_bit_cast(unsigned int, x);
    unsigned int r = (u + 0x7FFFu + ((u >> 16) & 1u)) >> 16;
    return (unsigned short)r;
}
__device__ inline float bf2f(unsigned short v) {
    unsigned int u = ((unsigned int)v) << 16;
    return __builtin_bit_cast(float, u);
}

__device__ __forceinline__ void stage16(const unsigned short* gp, unsigned short* lp) {
    __builtin_amdgcn_global_load_lds(
        (const __attribute__((address_space(1))) unsigned int*)(const void*)gp,
        (__attribute__((address_space(3))) unsigned int*)(void*)lp, 16, 0, 0);
}

// ------- init: zero z, z16, cost, rowsqP, cnts, psi-plane0 pad, t=0 out slice -------
__global__ __launch_bounds__(256) void init_kernel(float* __restrict__ z,
                                                   unsigned short* __restrict__ z16,
                                                   float* __restrict__ cost,
                                                   float* __restrict__ rowsqP,
                                                   unsigned short* __restrict__ psi0,
                                                   int* __restrict__ cnts,
                                                   float* __restrict__ out) {
    size_t idx = (size_t)blockIdx.x * blockDim.x + threadIdx.x;
    size_t stride = (size_t)gridDim.x * blockDim.x;
    for (size_t i = idx; i < NS; i += stride) { z[i] = 0.f; z16[i] = 0; }
    const size_t NO = (size_t)B_QRY * S_ANCH;
    for (size_t i = idx; i < NO; i += stride) {
        size_t b = i >> 10, s = i & 1023;
        out[b * (size_t)(F_NUM * S_ANCH) + s] = 0.f;
    }
    const size_t NR = (size_t)NPART * N_TOT;
    for (size_t i = idx; i < NR; i += stride) rowsqP[i] = 0.f;
    const size_t NPAD = (size_t)N_TOT * (D_PAD - D_DIM);
    for (size_t i = idx; i < NPAD; i += stride) {
        size_t n = i / (D_PAD - D_DIM), c = i % (D_PAD - D_DIM);
        psi0[n * D_PAD + D_DIM + c] = 0;
    }
    for (size_t i = idx; i < 36 * 48; i += stride) cnts[i] = 0;
    if (idx == 0) cost[0] = 0.f;
}

// ---------------- ALL c_t planes in one pass over c_s ----------------
__global__ __launch_bounds__(256) void c_all_kernel(const float* __restrict__ cs,
                                                    unsigned short* __restrict__ cT,
                                                    float* __restrict__ cfp, W190 W) {
    __shared__ float tile[32][65];
    int d0 = blockIdx.x * 64, s0 = blockIdx.y * 32;
    int t = threadIdx.x;
    int d_l = t & 63, s_base = t >> 6;
    int d = d0 + d_l;
    bool dok = (d < D_DIM);
    float creg[8][F_NUM];
#pragma unroll
    for (int it = 0; it < 8; it++) {
        int s = s0 + s_base + it * 4;
        const float* p = cs + ((size_t)s * D_DIM + d) * F_NUM;
#pragma unroll
        for (int f = 0; f < F_NUM; f++) creg[it][f] = dok ? p[f] : 0.f;
    }
    for (int j = 0; j < N_TV; j++) {
        float v[8];
#pragma unroll
        for (int it = 0; it < 8; it++) {
            float s = 0.f;
#pragma unroll
            for (int f = 0; f < F_NUM; f++) s += creg[it][f] * W.w[j][f];
            v[it] = s;
            tile[s_base + it * 4][d_l] = s;
        }
        if ((j & 1) == 0 && j >= 2 && dok) {
            int gi = (j >> 1) - 1;
#pragma unroll
            for (int it = 0; it < 8; it++)
                cfp[(size_t)gi * SD + (size_t)(s0 + s_base + it * 4) * D_DIM + d] = v[it];
        }
        __syncthreads();
        int s_l = t & 31, dr = t >> 5;
#pragma unroll
        for (int p8 = 0; p8 < 8; p8++) {
            int dd = dr + p8 * 8;
            cT[(size_t)j * CST + (size_t)(d0 + dd) * S_ANCH + s0 + s_l] = f2bf(tile[s_l][dd]);
        }
        __syncthreads();
    }
}

// ---------------- ALL psi_t planes: conv once, 19 freq-dots ----------------
__global__ __launch_bounds__(256) void conv_psi_all_kernel(const float* __restrict__ data,
                                                           const float* __restrict__ inputs,
                                                           const float* __restrict__ cw,
                                                           const float* __restrict__ cb,
                                                           unsigned short* __restrict__ psi_all,
                                                           W190 W) {
    __shared__ float wsh[720];
    __shared__ float bsh[80];
    for (int i = threadIdx.x; i < 720; i += 256) wsh[i] = cw[i];
    for (int i = threadIdx.x; i < 80; i += 256) bsh[i] = cb[i];
    __syncthreads();
    size_t idx = (size_t)blockIdx.x * 256 + threadIdx.x;
    if (idx >= (size_t)N_TOT * 8 * 169) return;
    int pos = (int)(idx % 169);
    int rest = (int)(idx / 169);
    int c8 = rest & 7;
    int n = rest >> 3;
    int oi = pos / 13, oj = pos % 13;
    const float* x = (n < S_ANCH) ? (data + (size_t)n * 784)
                                  : (inputs + (size_t)(n - S_ANCH) * 784);
    float vin[9];
#pragma unroll
    for (int kh = 0; kh < 3; kh++)
#pragma unroll
        for (int kw = 0; kw < 3; kw++)
            vin[kh * 3 + kw] = x[(2 * oi + kh) * 28 + (2 * oj + kw)];
    float s[F_NUM];
#pragma unroll
    for (int f = 0; f < F_NUM; f++) {
        int co = f * 8 + c8;
        float acc = bsh[co];
#pragma unroll
        for (int t = 0; t < 9; t++) acc += vin[t] * wsh[co * 9 + t];
        s[f] = acc;
    }
    size_t base = (size_t)n * D_PAD + c8 * 169 + pos;
#pragma unroll
    for (int j = 0; j < N_TV; j++) {
        float p = 0.f;
#pragma unroll
        for (int f = 0; f < F_NUM; f++) p += s[f] * W.w[j][f];
        psi_all[(size_t)j * PSIP + base] = f2bf(p);
    }
}

// ------- rowsq of psi plane 0 (for the t=0 shortcut: u == psi) -------
__global__ __launch_bounds__(256) void rowsq_psi_kernel(const unsigned short* __restrict__ psi0,
                                                        float* __restrict__ rowsqP) {
    int wv = threadIdx.x >> 6, lane = threadIdx.x & 63;
    int r = blockIdx.x * 4 + wv;
    const unsigned short* row = psi0 + (size_t)r * D_PAD;
    float s = 0.f;
    for (int c = lane; c < D_PAD / 8; c += 64) {
        int4 v = *(const int4*)(row + c * 8);
        const unsigned short* u = (const unsigned short*)&v;
#pragma unroll
        for (int e = 0; e < 8; e++) { float f = bf2f(u[e]); s += f * f; }
    }
    s += __shfl_xor(s, 1); s += __shfl_xor(s, 2); s += __shfl_xor(s, 4);
    s += __shfl_xor(s, 8); s += __shfl_xor(s, 16); s += __shfl_xor(s, 32);
    if (lane == 0) rowsqP[r] = s;   // slot 0; slots 1..43 zeroed by init
}

// ======== fused per-eval kernel: GEMM1 tiles -> signal -> GEMM2 tiles ========
struct EvArgs {
    const unsigned short* Az;   // GEMM1 A (z16 or zt16)
    const unsigned short* Bc;   // GEMM1 B (c16T plane)
    const unsigned short* psi16;
    unsigned short* u16;
    float* rowsqP;
    int do_cost; const float* cfp; float* cost;
    const unsigned short* U2;   // GEMM2 operand (u16, or psi plane 0 on shortcut)
    float* zcur; unsigned short* accb16; unsigned short* zt16; float* outp;
    int first, finish, tout; float alpha, h6;
    int has_phaseA;
    int* cnt;                   // 48 row-group counters for this eval
};

__global__ __launch_bounds__(256) void eval_kernel(EvArgs g) {
    __shared__ __align__(16) unsigned short As[6][64][32];
    __shared__ __align__(16) unsigned short Bs[6][64][32];
    __shared__ float sclM[64], ahM[64], sclN[64], ahN[64];
    __shared__ float red4[4];
    const int t = threadIdx.x;
    const int lane = t & 63, wv = t >> 6;
    const int wm = (wv >> 1) * 32, wn = (wv & 1) * 32;
    const int lr = lane & 15, lg = lane >> 4;
    const int srow = lane >> 2;
    const int gch = (lane & 3) ^ ((lane >> 3) & 3);
    const int sl = lg ^ ((lr >> 1) & 3);
    const int bid = blockIdx.x;

    auto runK = [&](const unsigned short* Abase, const unsigned short* Bbase,
                    int nt, f32x4 (&acc)[2][2]) {
        auto STAGE = [&](int k) {
            int buf = k % 6;
            stage16(Abase + (k << 5), &As[buf][wv * 16][0]);
            stage16(Bbase + (k << 5), &Bs[buf][wv * 16][0]);
        };
        auto COMPUTE = [&](int k) {
            int buf = k % 6;
            bf16x8 af[2], bf[2];
#pragma unroll
            for (int i = 0; i < 2; i++)
                af[i] = *(const bf16x8*)&As[buf][wm + i * 16 + lr][sl * 8];
#pragma unroll
            for (int j = 0; j < 2; j++)
                bf[j] = *(const bf16x8*)&Bs[buf][wn + j * 16 + lr][sl * 8];
#pragma unroll
            for (int i = 0; i < 2; i++)
#pragma unroll
                for (int j = 0; j < 2; j++)
                    acc[i][j] = __builtin_amdgcn_mfma_f32_16x16x32_bf16(af[i], bf[j], acc[i][j], 0, 0, 0);
        };
        STAGE(0); STAGE(1); STAGE(2); STAGE(3); STAGE(4);
        for (int k = 0; k < nt - 5; ++k) {
            asm volatile("s_waitcnt vmcnt(8)" ::: "memory");
            __builtin_amdgcn_s_barrier();
            __builtin_amdgcn_sched_barrier(0);
            STAGE(k + 5);
            COMPUTE(k);
        }
        asm volatile("s_waitcnt vmcnt(8)" ::: "memory");
        __builtin_amdgcn_s_barrier(); __builtin_amdgcn_sched_barrier(0);
        COMPUTE(nt - 5);
        asm volatile("s_waitcnt vmcnt(6)" ::: "memory");
        __builtin_amdgcn_s_barrier(); __builtin_amdgcn_sched_barrier(0);
        COMPUTE(nt - 4);
        asm volatile("s_waitcnt vmcnt(4)" ::: "memory");
        __builtin_amdgcn_s_barrier(); __builtin_amdgcn_sched_barrier(0);
        COMPUTE(nt - 3);
        asm volatile("s_waitcnt vmcnt(2)" ::: "memory");
        __builtin_amdgcn_s_barrier(); __builtin_amdgcn_sched_barrier(0);
        COMPUTE(nt - 2);
        asm volatile("s_waitcnt vmcnt(0)" ::: "memory");
        __builtin_amdgcn_s_barrier(); __builtin_amdgcn_sched_barrier(0);
        COMPUTE(nt - 1);
    };

    // ================= phase A: GEMM1 tiles (1056) =================
    if (g.has_phaseA) {
        for (int tt = bid; tt < 22 * 48; tt += NB_EV) {
            int swz = (tt & 7) * 132 + (tt >> 3);
            int bx = swz % 22, by = swz / 22;
            int bm = by * 64, bn = bx * 64;
            __syncthreads();   // LDS reuse guard across tiles
            const bool docost = g.do_cost && (bm < S_ANCH);
            unsigned short psi_r[2][4][2];
            float cfp_r[2][4][2];
#pragma unroll
            for (int i = 0; i < 2; i++)
#pragma unroll
                for (int reg = 0; reg < 4; reg++) {
                    int m = bm + wm + i * 16 + lg * 4 + reg;
#pragma unroll
                    for (int j = 0; j < 2; j++) {
                        int n = bn + wn + j * 16 + lr;
                        psi_r[i][reg][j] = g.psi16[(size_t)m * D_PAD + n];
                        if (docost)
                            cfp_r[i][reg][j] = (n < D_DIM) ? g.cfp[(size_t)m * D_DIM + n] : 0.f;
                    }
                }
            __builtin_amdgcn_sched_barrier(0);

            f32x4 acc[2][2];
#pragma unroll
            for (int i = 0; i < 2; i++)
#pragma unroll
                for (int j = 0; j < 2; j++) acc[i][j] = (f32x4){0.f, 0.f, 0.f, 0.f};
            const unsigned short* Abase = g.Az + (size_t)(bm + wv * 16 + srow) * S_ANCH + gch * 8;
            const unsigned short* Bbase = g.Bc + (size_t)(bn + wv * 16 + srow) * S_ANCH + gch * 8;
            runK(Abase, Bbase, S_ANCH >> 5, acc);

            float cst = 0.f;
#pragma unroll
            for (int i = 0; i < 2; i++) {
#pragma unroll
                for (int reg = 0; reg < 4; reg++) {
                    int m = bm + wm + i * 16 + lg * 4 + reg;
                    float sq = 0.f;
#pragma unroll
                    for (int j = 0; j < 2; j++) {
                        int n = bn + wn + j * 16 + lr;
                        float v = acc[i][j][reg];
                        bool nok = n < D_DIM;
                        if (docost) cst += v * cfp_r[i][reg][j];
                        if (nok) v += bf2f(psi_r[i][reg][j]);
                        else v = 0.f;
                        g.u16[(size_t)m * D_PAD + n] = f2bf(v);
                        sq += v * v;
                    }
                    sq += __shfl_xor(sq, 1);
                    sq += __shfl_xor(sq, 2);
                    sq += __shfl_xor(sq, 4);
                    sq += __shfl_xor(sq, 8);
                    if (lr == 0)
                        g.rowsqP[(size_t)(bx * 2 + (wn >> 5)) * N_TOT + m] = sq;
                }
            }
            if (docost) {
                cst += __shfl_xor(cst, 1); cst += __shfl_xor(cst, 2);
                cst += __shfl_xor(cst, 4); cst += __shfl_xor(cst, 8);
                cst += __shfl_xor(cst, 16); cst += __shfl_xor(cst, 32);
                if (lane == 0) red4[wv] = cst;
                __syncthreads();
                if (t == 0) atomicAdd(g.cost, red4[0] + red4[1] + red4[2] + red4[3]);
            }
            // release: stores drained by syncthreads, fence -> signal row-group done
            __syncthreads();
            if (t == 0) {
                __threadfence();
                __hip_atomic_fetch_add(&g.cnt[by], 1, __ATOMIC_RELEASE, __HIP_MEMORY_SCOPE_AGENT);
            }
        }
    }

    // ================= phase B: GEMM2 tiles (768) =================
    for (int tt = bid; tt < 16 * 48; tt += NB_EV) {
        int swz = (tt & 7) * 96 + (tt >> 3);
        int bx = swz % 16, by = swz / 16;
        int bm = by * 64, bn = bx * 64;
        __syncthreads();   // LDS reuse guard
        if (g.has_phaseA) {
            if (t == 0) {
                while (__hip_atomic_load(&g.cnt[by], __ATOMIC_RELAXED, __HIP_MEMORY_SCOPE_AGENT) < 22)
                    __builtin_amdgcn_s_sleep(8);
                while (__hip_atomic_load(&g.cnt[bx], __ATOMIC_RELAXED, __HIP_MEMORY_SCOPE_AGENT) < 22)
                    __builtin_amdgcn_s_sleep(8);
                __threadfence();   // acquire: see released u16/rowsqP
            }
            __syncthreads();
        }
        // squash stats from partial row sums
        if (t < 128) {
            int r = (t < 64) ? (bm + t) : (bn + (t - 64));
            float tot = 0.f;
#pragma unroll
            for (int c = 0; c < NPART; c++) tot += g.rowsqP[(size_t)c * N_TOT + r];
            float norm = sqrtf(tot + 1e-6f);
            float sg = 1.f / (1.f + __expf(-norm));
            float sc = sg / norm;
            float a = 0.5f * tot * sc * sc;
            if (t < 64) { sclM[t] = sc; ahM[t] = a; }
            else        { sclN[t - 64] = sc; ahN[t - 64] = a; }
        }
        // T14 early epilogue-input loads
        float zc_r[2][4][2];
        unsigned short ab_r[2][4][2];
#pragma unroll
        for (int i = 0; i < 2; i++)
#pragma unroll
            for (int reg = 0; reg < 4; reg++) {
                int m = bm + wm + i * 16 + lg * 4 + reg;
#pragma unroll
                for (int j = 0; j < 2; j++) {
                    int n = bn + wn + j * 16 + lr;
                    size_t idx = (size_t)m * S_ANCH + n;
                    zc_r[i][reg][j] = g.zcur[idx];
                    ab_r[i][reg][j] = g.accb16[idx];
                }
            }
        __builtin_amdgcn_sched_barrier(0);

        f32x4 acc[2][2];
#pragma unroll
        for (int i = 0; i < 2; i++)
#pragma unroll
            for (int j = 0; j < 2; j++) acc[i][j] = (f32x4){0.f, 0.f, 0.f, 0.f};
        const unsigned short* Abase = g.U2 + (size_t)(bm + wv * 16 + srow) * D_PAD + gch * 8;
        const unsigned short* Bbase = g.U2 + (size_t)(bn + wv * 16 + srow) * D_PAD + gch * 8;
        runK(Abase, Bbase, D_K >> 5, acc);

        __syncthreads();  // stats visibility
#pragma unroll
        for (int i = 0; i < 2; i++) {
#pragma unroll
            for (int reg = 0; reg < 4; reg++) {
                int mi = wm + i * 16 + lg * 4 + reg;
                int m = bm + mi;
                float sm = sclM[mi], am = ahM[mi];
#pragma unroll
                for (int j = 0; j < 2; j++) {
                    int ni = wn + j * 16 + lr;
                    int n = bn + ni;
                    float uv = acc[i][j][reg] * sm * sclN[ni];
                    float kv = __expf(uv - am - ahN[ni]) * uv;
                    size_t idx = (size_t)m * S_ANCH + n;
                    if (!g.finish) {
                        float ab = g.first ? kv : (bf2f(ab_r[i][reg][j]) + 2.0f * kv);
                        g.accb16[idx] = f2bf(ab);
                        float zt = zc_r[i][reg][j] + g.alpha * kv;
                        g.zt16[idx] = f2bf(zt);
                    } else {
                        float z = zc_r[i][reg][j] + g.h6 * (bf2f(ab_r[i][reg][j]) + kv);
                        g.zcur[idx] = z;
                        g.zt16[idx] = f2bf(z);
                        if (m >= S_ANCH)
                            g.outp[(size_t)(m - S_ANCH) * (F_NUM * S_ANCH)
                                   + (size_t)g.tout * S_ANCH + n] = z;
                    }
                }
            }
        }
    }
}

// ---------------- t9 cost quadratic form (once, after RK4) ----------------
__global__ __launch_bounds__(256) void cost_gemm(const unsigned short* __restrict__ A,
                                                 const unsigned short* __restrict__ B,
                                                 const float* __restrict__ cfp,
                                                 float* __restrict__ cost) {
    __shared__ __align__(16) unsigned short As[6][64][32];
    __shared__ __align__(16) unsigned short Bs[6][64][32];
    __shared__ float red4[4];
    const int nbk = gridDim.x;
    const int lin = blockIdx.x;
    const int swz = (lin & 7) * (nbk >> 3) + (lin >> 3);
    const int bx = swz % 22, by = swz / 22;
    const int bm = by * 64, bn = bx * 64;
    const int t = threadIdx.x;
    const int lane = t & 63, wv = t >> 6;
    const int wm = (wv >> 1) * 32, wn = (wv & 1) * 32;
    const int lr = lane & 15, lg = lane >> 4;
    const int srow = lane >> 2;
    const int gch = (lane & 3) ^ ((lane >> 3) & 3);
    const int sl = lg ^ ((lr >> 1) & 3);

    f32x4 acc[2][2];
#pragma unroll
    for (int i = 0; i < 2; i++)
#pragma unroll
        for (int j = 0; j < 2; j++) acc[i][j] = (f32x4){0.f, 0.f, 0.f, 0.f};

    const unsigned short* Abase = A + (size_t)(bm + wv * 16 + srow) * S_ANCH + gch * 8;
    const unsigned short* Bbase = B + (size_t)(bn + wv * 16 + srow) * S_ANCH + gch * 8;
    auto STAGE = [&](int k) {
        int buf = k % 6;
        stage16(Abase + (k << 5), &As[buf][wv * 16][0]);
        stage16(Bbase + (k << 5), &Bs[buf][wv * 16][0]);
    };
    auto COMPUTE = [&](int k) {
        int buf = k % 6;
        bf16x8 af[2], bf[2];
#pragma unroll
        for (int i = 0; i < 2; i++)
            af[i] = *(const bf16x8*)&As[buf][wm + i * 16 + lr][sl * 8];
#pragma unroll
        for (int j = 0; j < 2; j++)
            bf[j] = *(const bf16x8*)&Bs[buf][wn + j * 16 + lr][sl * 8];
#pragma unroll
        for (int i = 0; i < 2; i++)
#pragma unroll
            for (int j = 0; j < 2; j++)
                acc[i][j] = __builtin_amdgcn_mfma_f32_16x16x32_bf16(af[i], bf[j], acc[i][j], 0, 0, 0);
    };
    const int nt = S_ANCH >> 5;
    STAGE(0); STAGE(1); STAGE(2); STAGE(3); STAGE(4);
    for (int k = 0; k < nt - 5; ++k) {
        asm volatile("s_waitcnt vmcnt(8)" ::: "memory");
        __builtin_amdgcn_s_barrier();
        __builtin_amdgcn_sched_barrier(0);
        STAGE(k + 5);
        COMPUTE(k);
    }
    asm volatile("s_waitcnt vmcnt(8)" ::: "memory");
    __builtin_amdgcn_s_barrier(); __builtin_amdgcn_sched_barrier(0);
    COMPUTE(nt - 5);
    asm volatile("s_waitcnt vmcnt(6)" ::: "memory");
    __builtin_amdgcn_s_barrier(); __builtin_amdgcn_sched_barrier(0);
    COMPUTE(nt - 4);
    asm volatile("s_waitcnt vmcnt(4)" ::: "memory");
    __builtin_amdgcn_s_barrier(); __builtin_amdgcn_sched_barrier(0);
    COMPUTE(nt - 3);
    asm volatile("s_waitcnt vmcnt(2)" ::: "memory");
    __builtin_amdgcn_s_barrier(); __builtin_amdgcn_sched_barrier(0);
    COMPUTE(nt - 2);
    asm volatile("s_waitcnt vmcnt(0)" ::: "memory");
    __builtin_amdgcn_s_barrier(); __builtin_amdgcn_sched_barrier(0);
    COMPUTE(nt - 1);

    float s = 0.f;
#pragma unroll
    for (int i = 0; i < 2; i++)
#pragma unroll
        for (int reg = 0; reg < 4; reg++) {
            int m = bm + wm + i * 16 + lg * 4 + reg;
#pragma unroll
            for (int j = 0; j < 2; j++) {
                int n = bn + wn + j * 16 + lr;
                if (n < D_DIM) s += acc[i][j][reg] * cfp[(size_t)m * D_DIM + n];
            }
        }
    s += __shfl_xor(s, 1); s += __shfl_xor(s, 2); s += __shfl_xor(s, 4);
    s += __shfl_xor(s, 8); s += __shfl_xor(s, 16); s += __shfl_xor(s, 32);
    if (lane == 0) red4[wv] = s;
    __syncthreads();
    if (t == 0) atomicAdd(cost, red4[0] + red4[1] + red4[2] + red4[3]);
}

// ---------------- final: add conv_w/b square norm ----------------
__global__ __launch_bounds__(256) void final_kernel(const float* __restrict__ cw,
                                                    const float* __restrict__ cb,
                                                    const float* __restrict__ cost,
                                                    float* __restrict__ out) {
    float s = 0.f;
    for (int i = threadIdx.x; i < 720; i += 256) s += cw[i] * cw[i];
    for (int i = threadIdx.x; i < 80; i += 256) s += cb[i] * cb[i];
    for (int o = 32; o > 0; o >>= 1) s += __shfl_down(s, o);
    __shared__ float red[4];
    if ((threadIdx.x & 63) == 0) red[threadIdx.x >> 6] = s;
    __syncthreads();
    if (threadIdx.x == 0) out[0] = red[0] + red[1] + red[2] + red[3] + cost[0] / 10.0f;
}

// ---------------- host ----------------
extern "C" void kernel_launch(void* const* d_in, const int* in_sizes, int n_in,
                              void* d_out, int out_size, void* d_ws, size_t ws_size,
                              hipStream_t stream) {
    (void)in_sizes; (void)n_in; (void)out_size; (void)ws_size;
    const float* data   = (const float*)d_in[0];
    const float* inputs = (const float*)d_in[1];
    const float* conv_w = (const float*)d_in[2];
    const float* conv_b = (const float*)d_in[3];
    const float* c_s    = (const float*)d_in[4];
    float* out = (float*)d_out;

    char* ws = (char*)d_ws;
    size_t off = 0;
    auto alloc = [&](size_t bytes) {
        char* p = ws + off; off += (bytes + 255) & ~(size_t)255; return p;
    };
    unsigned short* c16T_all = (unsigned short*)alloc((size_t)N_TV * CST * 2);   // 54.8 MB
    float*          cfp_all  = (float*)alloc((size_t)9 * SD * 4);                // 49.8 MB
    unsigned short* psi_all  = (unsigned short*)alloc((size_t)N_TV * PSIP * 2);  // 164.4 MB
    unsigned short* u16      = (unsigned short*)alloc(PSIP * 2);
    float*          z_cur    = (float*)alloc(NS * 4);
    unsigned short* z16      = (unsigned short*)alloc(NS * 2);
    unsigned short* zt16     = (unsigned short*)alloc(NS * 2);
    unsigned short* accb16   = (unsigned short*)alloc(NS * 2);
    float*          rowsqP   = (float*)alloc((size_t)NPART * N_TOT * 4);
    float*          cost     = (float*)alloc(64);
    int*            cnts     = (int*)alloc(36 * 48 * 4);

    const double TAU_D = 6.2831853071795864769;
    float ts[F_NUM];
    for (int i = 0; i < F_NUM; i++) ts[i] = (float)((double)i / 9.0);
    W190 Wall;
    for (int j = 0; j < N_TV; j++) {
        float tt;
        if ((j & 1) == 0) tt = ts[j >> 1];
        else {
            int i = j >> 1;
            float h = ts[i + 1] - ts[i];
            tt = ts[i] + 0.5f * h;
        }
        for (int f = 0; f < F_NUM; f++) {
            float coeff = (float)(TAU_D * f);
            float targ = tt * coeff;
            Wall.w[j][f] = (float)cos((double)targ);
        }
    }

    init_kernel<<<2048, 256, 0, stream>>>(z_cur, z16, cost, rowsqP, psi_all, cnts, out);
    c_all_kernel<<<dim3(22, 32), 256, 0, stream>>>(c_s, c16T_all, cfp_all, Wall);
    const int conv_blocks = (int)(((size_t)N_TOT * 8 * 169 + 255) / 256);
    conv_psi_all_kernel<<<conv_blocks, 256, 0, stream>>>(data, inputs, conv_w, conv_b,
                                                         psi_all, Wall);
    rowsq_psi_kernel<<<N_TOT / 4, 256, 0, stream>>>(psi_all, rowsqP);

    EvArgs g = {};
    g.u16 = u16; g.rowsqP = rowsqP; g.cost = cost;
    g.zcur = z_cur; g.accb16 = accb16; g.outp = out;

    int ev = 0;
    for (int i = 0; i < 9; i++) {
        float h = ts[i + 1] - ts[i];
        int js[4] = {2 * i, 2 * i + 1, 2 * i + 1, 2 * i + 2};
        float alphas[3] = {0.5f * h, 0.5f * h, h};
        for (int e = 0; e < 4; e++, ev++) {
            int j = js[e];
            const bool shortcut = (i == 0 && e == 0);   // z == 0 -> u == psi
            g.has_phaseA = shortcut ? 0 : 1;
            g.Az = (e == 0) ? z16 : zt16;
            g.Bc = c16T_all + (size_t)j * CST;
            g.psi16 = psi_all + (size_t)j * PSIP;
            g.do_cost = (e == 0 && i >= 1) ? 1 : 0;
            g.cfp = (i >= 1) ? (cfp_all + (size_t)(i - 1) * SD) : cfp_all;
            g.U2 = shortcut ? psi_all : u16;
            g.first = (e == 0); g.finish = (e == 3);
            g.alpha = (e < 3) ? alphas[e] : 0.f;
            g.h6 = h / 6.0f; g.tout = i + 1;
            g.zt16 = (e < 3) ? zt16 : z16;
            g.cnt = cnts + ev * 48;
            eval_kernel<<<NB_EV, 256, 0, stream>>>(g);
        }
    }
    // cost contribution at t_9 (z16 holds z_{t9})
    cost_gemm<<<22 * 16, 256, 0, stream>>>(z16, c16T_all + (size_t)18 * CST,
                                           cfp_all + (size_t)8 * SD, cost);

    final_kernel<<<1, 256, 0, stream>>>(conv_w, conv_b, cost, out + OUT_Z);
}

// Round 16
// 2249.598 us; speedup vs baseline: 2.5291x; 2.5291x over previous
//
#include <hip/hip_runtime.h>
#include <math.h>

#define S_ANCH 1024
#define B_QRY  2048
#define N_TOT  3072
#define D_DIM  1352
#define D_PAD  1408   // padded D: u16/psi stride, c16T rows
#define D_K    1376   // GEMM2 K extent (covers D_DIM, multiple of 32)
#define F_NUM  10
#define N_TV   19
#define NPART  44     // 22 n-tiles * 2 wave-halves in GEMM1

static const size_t SD    = (size_t)S_ANCH * D_DIM;
static const size_t NS    = (size_t)N_TOT * S_ANCH;
static const size_t CST   = (size_t)D_PAD * S_ANCH;   // one c16T plane
static const size_t PSIP  = (size_t)N_TOT * D_PAD;    // one psi plane
static const size_t OUT_Z = (size_t)B_QRY * F_NUM * S_ANCH;

typedef __attribute__((ext_vector_type(8))) short bf16x8;
typedef __attribute__((ext_vector_type(4))) float f32x4;

struct W190 { float w[N_TV][F_NUM]; };

__device__ inline unsigned short f2bf(float x) {
    unsigned int u = __builtin_bit_cast(unsigned int, x);
    unsigned int r = (u + 0x7FFFu + ((u >> 16) & 1u)) >> 16;
    return (unsigned short)r;
}
__device__ inline float bf2f(unsigned short v) {
    unsigned int u = ((unsigned int)v) << 16;
    return __builtin_bit_cast(float, u);
}

__device__ __forceinline__ void stage16(const unsigned short* gp, unsigned short* lp) {
    __builtin_amdgcn_global_load_lds(
        (const __attribute__((address_space(1))) unsigned int*)(const void*)gp,
        (__attribute__((address_space(3))) unsigned int*)(void*)lp, 16, 0, 0);
}

// ------- init: zero z, z16, cost, rowsqP, psi-plane0 pad, t=0 out slice -------
__global__ __launch_bounds__(256) void init_kernel(float* __restrict__ z,
                                                   unsigned short* __restrict__ z16,
                                                   float* __restrict__ cost,
                                                   float* __restrict__ rowsqP,
                                                   unsigned short* __restrict__ psi0,
                                                   float* __restrict__ out) {
    size_t idx = (size_t)blockIdx.x * blockDim.x + threadIdx.x;
    size_t stride = (size_t)gridDim.x * blockDim.x;
    for (size_t i = idx; i < NS; i += stride) { z[i] = 0.f; z16[i] = 0; }
    const size_t NO = (size_t)B_QRY * S_ANCH;
    for (size_t i = idx; i < NO; i += stride) {
        size_t b = i >> 10, s = i & 1023;
        out[b * (size_t)(F_NUM * S_ANCH) + s] = 0.f;
    }
    const size_t NR = (size_t)NPART * N_TOT;
    for (size_t i = idx; i < NR; i += stride) rowsqP[i] = 0.f;
    const size_t NPAD = (size_t)N_TOT * (D_PAD - D_DIM);
    for (size_t i = idx; i < NPAD; i += stride) {
        size_t n = i / (D_PAD - D_DIM), c = i % (D_PAD - D_DIM);
        psi0[n * D_PAD + D_DIM + c] = 0;
    }
    if (idx == 0) cost[0] = 0.f;
}

// ---------------- ALL c_t planes in one pass over c_s ----------------
__global__ __launch_bounds__(256) void c_all_kernel(const float* __restrict__ cs,
                                                    unsigned short* __restrict__ cT,
                                                    float* __restrict__ cfp, W190 W) {
    __shared__ float tile[32][65];
    int d0 = blockIdx.x * 64, s0 = blockIdx.y * 32;
    int t = threadIdx.x;
    int d_l = t & 63, s_base = t >> 6;
    int d = d0 + d_l;
    bool dok = (d < D_DIM);
    float creg[8][F_NUM];
#pragma unroll
    for (int it = 0; it < 8; it++) {
        int s = s0 + s_base + it * 4;
        const float* p = cs + ((size_t)s * D_DIM + d) * F_NUM;
#pragma unroll
        for (int f = 0; f < F_NUM; f++) creg[it][f] = dok ? p[f] : 0.f;
    }
    for (int j = 0; j < N_TV; j++) {
        float v[8];
#pragma unroll
        for (int it = 0; it < 8; it++) {
            float s = 0.f;
#pragma unroll
            for (int f = 0; f < F_NUM; f++) s += creg[it][f] * W.w[j][f];
            v[it] = s;
            tile[s_base + it * 4][d_l] = s;
        }
        if ((j & 1) == 0 && j >= 2 && dok) {
            int gi = (j >> 1) - 1;
#pragma unroll
            for (int it = 0; it < 8; it++)
                cfp[(size_t)gi * SD + (size_t)(s0 + s_base + it * 4) * D_DIM + d] = v[it];
        }
        __syncthreads();
        int s_l = t & 31, dr = t >> 5;
#pragma unroll
        for (int p8 = 0; p8 < 8; p8++) {
            int dd = dr + p8 * 8;
            cT[(size_t)j * CST + (size_t)(d0 + dd) * S_ANCH + s0 + s_l] = f2bf(tile[s_l][dd]);
        }
        __syncthreads();
    }
}

// ---------------- ALL psi_t planes: conv once, 19 freq-dots ----------------
__global__ __launch_bounds__(256) void conv_psi_all_kernel(const float* __restrict__ data,
                                                           const float* __restrict__ inputs,
                                                           const float* __restrict__ cw,
                                                           const float* __restrict__ cb,
                                                           unsigned short* __restrict__ psi_all,
                                                           W190 W) {
    __shared__ float wsh[720];
    __shared__ float bsh[80];
    for (int i = threadIdx.x; i < 720; i += 256) wsh[i] = cw[i];
    for (int i = threadIdx.x; i < 80; i += 256) bsh[i] = cb[i];
    __syncthreads();
    size_t idx = (size_t)blockIdx.x * 256 + threadIdx.x;
    if (idx >= (size_t)N_TOT * 8 * 169) return;
    int pos = (int)(idx % 169);
    int rest = (int)(idx / 169);
    int c8 = rest & 7;
    int n = rest >> 3;
    int oi = pos / 13, oj = pos % 13;
    const float* x = (n < S_ANCH) ? (data + (size_t)n * 784)
                                  : (inputs + (size_t)(n - S_ANCH) * 784);
    float vin[9];
#pragma unroll
    for (int kh = 0; kh < 3; kh++)
#pragma unroll
        for (int kw = 0; kw < 3; kw++)
            vin[kh * 3 + kw] = x[(2 * oi + kh) * 28 + (2 * oj + kw)];
    float s[F_NUM];
#pragma unroll
    for (int f = 0; f < F_NUM; f++) {
        int co = f * 8 + c8;
        float acc = bsh[co];
#pragma unroll
        for (int t = 0; t < 9; t++) acc += vin[t] * wsh[co * 9 + t];
        s[f] = acc;
    }
    size_t base = (size_t)n * D_PAD + c8 * 169 + pos;
#pragma unroll
    for (int j = 0; j < N_TV; j++) {
        float p = 0.f;
#pragma unroll
        for (int f = 0; f < F_NUM; f++) p += s[f] * W.w[j][f];
        psi_all[(size_t)j * PSIP + base] = f2bf(p);
    }
}

// ------- rowsq of psi plane 0 (for the t=0 shortcut: u == psi) -------
__global__ __launch_bounds__(256) void rowsq_psi_kernel(const unsigned short* __restrict__ psi0,
                                                        float* __restrict__ rowsqP) {
    int wv = threadIdx.x >> 6, lane = threadIdx.x & 63;
    int r = blockIdx.x * 4 + wv;
    const unsigned short* row = psi0 + (size_t)r * D_PAD;
    float s = 0.f;
    for (int c = lane; c < D_PAD / 8; c += 64) {
        int4 v = *(const int4*)(row + c * 8);
        const unsigned short* u = (const unsigned short*)&v;
#pragma unroll
        for (int e = 0; e < 8; e++) { float f = bf2f(u[e]); s += f * f; }
    }
    s += __shfl_xor(s, 1); s += __shfl_xor(s, 2); s += __shfl_xor(s, 4);
    s += __shfl_xor(s, 8); s += __shfl_xor(s, 16); s += __shfl_xor(s, 32);
    if (lane == 0) rowsqP[r] = s;   // slot 0; slots 1..43 zeroed by init
}

// ---- MFMA GEMM (NT), 64x64 tile, BK=32, 6-buf depth-5 counted-vmcnt ----
// T14 epilogue-input prefetch before the K-loop (R13-verified +18%).
struct GemmArgs {
    const unsigned short* A; const unsigned short* B;
    int lda, ldb, K, gx;
    // MODE 0
    const unsigned short* psi16; unsigned short* u16; float* rowsqP;
    int do_cost;
    // MODE 0 (cost fusion) + MODE 2
    const float* cfp; float* cost;
    // MODE 1
    float* zcur; unsigned short* accb16; unsigned short* zt16; float* outp;
    int first, finish, tout; float alpha, h6;
};

template<int MODE>
__global__ __launch_bounds__(256) void mfma_gemm(GemmArgs g) {
    __shared__ __align__(16) unsigned short As[6][64][32];
    __shared__ __align__(16) unsigned short Bs[6][64][32];
    __shared__ float sclM[64], ahM[64], sclN[64], ahN[64];
    __shared__ float red4[4];
    const int nb = gridDim.x;
    const int lin = blockIdx.x;
    const int swz = (lin & 7) * (nb >> 3) + (lin >> 3);
    const int bx = swz % g.gx, by = swz / g.gx;
    const int bm = by * 64, bn = bx * 64;
    const int t = threadIdx.x;
    const int lane = t & 63, wv = t >> 6;
    const int wm = (wv >> 1) * 32, wn = (wv & 1) * 32;
    const int lr = lane & 15, lg = lane >> 4;
    const int srow = lane >> 2;
    const int gch = (lane & 3) ^ ((lane >> 3) & 3);
    const int sl = lg ^ ((lr >> 1) & 3);

    if (MODE == 1) {
        if (t < 128) {
            int r = (t < 64) ? (bm + t) : (bn + (t - 64));
            float tot = 0.f;
#pragma unroll
            for (int c = 0; c < NPART; c++) tot += g.rowsqP[(size_t)c * N_TOT + r];
            float norm = sqrtf(tot + 1e-6f);
            float sg = 1.f / (1.f + __expf(-norm));
            float sc = sg / norm;
            float a = 0.5f * tot * sc * sc;
            if (t < 64) { sclM[t] = sc; ahM[t] = a; }
            else        { sclN[t - 64] = sc; ahN[t - 64] = a; }
        }
    }

    // ---- T14: early epilogue-input loads (independent of MFMA results) ----
    const bool docost = (MODE == 0) && g.do_cost && (bm < S_ANCH);
    unsigned short psi_r[2][4][2];
    float cfp_r[2][4][2];
    float zc_r[2][4][2];
    unsigned short ab_r[2][4][2];
    if (MODE == 0) {
#pragma unroll
        for (int i = 0; i < 2; i++)
#pragma unroll
            for (int reg = 0; reg < 4; reg++) {
                int m = bm + wm + i * 16 + lg * 4 + reg;
#pragma unroll
                for (int j = 0; j < 2; j++) {
                    int n = bn + wn + j * 16 + lr;
                    psi_r[i][reg][j] = g.psi16[(size_t)m * D_PAD + n];
                    if (docost)
                        cfp_r[i][reg][j] = (n < D_DIM) ? g.cfp[(size_t)m * D_DIM + n] : 0.f;
                }
            }
    } else if (MODE == 1) {
#pragma unroll
        for (int i = 0; i < 2; i++)
#pragma unroll
            for (int reg = 0; reg < 4; reg++) {
                int m = bm + wm + i * 16 + lg * 4 + reg;
#pragma unroll
                for (int j = 0; j < 2; j++) {
                    int n = bn + wn + j * 16 + lr;
                    size_t idx = (size_t)m * S_ANCH + n;
                    zc_r[i][reg][j] = g.zcur[idx];
                    ab_r[i][reg][j] = g.accb16[idx];
                }
            }
    }
    __builtin_amdgcn_sched_barrier(0);   // pin early loads before staging

    f32x4 acc[2][2];
#pragma unroll
    for (int i = 0; i < 2; i++)
#pragma unroll
        for (int j = 0; j < 2; j++) acc[i][j] = (f32x4){0.f, 0.f, 0.f, 0.f};

    const unsigned short* Abase = g.A + (size_t)(bm + wv * 16 + srow) * g.lda + gch * 8;
    const unsigned short* Bbase = g.B + (size_t)(bn + wv * 16 + srow) * g.ldb + gch * 8;

    auto STAGE = [&](int k) {
        int buf = k % 6;
        stage16(Abase + (k << 5), &As[buf][wv * 16][0]);
        stage16(Bbase + (k << 5), &Bs[buf][wv * 16][0]);
    };
    auto COMPUTE = [&](int k) {
        int buf = k % 6;
        bf16x8 af[2], bf[2];
#pragma unroll
        for (int i = 0; i < 2; i++)
            af[i] = *(const bf16x8*)&As[buf][wm + i * 16 + lr][sl * 8];
#pragma unroll
        for (int j = 0; j < 2; j++)
            bf[j] = *(const bf16x8*)&Bs[buf][wn + j * 16 + lr][sl * 8];
#pragma unroll
        for (int i = 0; i < 2; i++)
#pragma unroll
            for (int j = 0; j < 2; j++)
                acc[i][j] = __builtin_amdgcn_mfma_f32_16x16x32_bf16(af[i], bf[j], acc[i][j], 0, 0, 0);
    };

    const int nt = g.K >> 5;   // 32 or 43; always > 6
    STAGE(0); STAGE(1); STAGE(2); STAGE(3); STAGE(4);
    for (int k = 0; k < nt - 5; ++k) {
        asm volatile("s_waitcnt vmcnt(8)" ::: "memory");
        __builtin_amdgcn_s_barrier();
        __builtin_amdgcn_sched_barrier(0);
        STAGE(k + 5);
        COMPUTE(k);
    }
    asm volatile("s_waitcnt vmcnt(8)" ::: "memory");
    __builtin_amdgcn_s_barrier(); __builtin_amdgcn_sched_barrier(0);
    COMPUTE(nt - 5);
    asm volatile("s_waitcnt vmcnt(6)" ::: "memory");
    __builtin_amdgcn_s_barrier(); __builtin_amdgcn_sched_barrier(0);
    COMPUTE(nt - 4);
    asm volatile("s_waitcnt vmcnt(4)" ::: "memory");
    __builtin_amdgcn_s_barrier(); __builtin_amdgcn_sched_barrier(0);
    COMPUTE(nt - 3);
    asm volatile("s_waitcnt vmcnt(2)" ::: "memory");
    __builtin_amdgcn_s_barrier(); __builtin_amdgcn_sched_barrier(0);
    COMPUTE(nt - 2);
    asm volatile("s_waitcnt vmcnt(0)" ::: "memory");
    __builtin_amdgcn_s_barrier(); __builtin_amdgcn_sched_barrier(0);
    COMPUTE(nt - 1);

    // ---------------- epilogues (inputs already in registers) ----------------
    if (MODE == 0) {
        float cst = 0.f;
#pragma unroll
        for (int i = 0; i < 2; i++) {
#pragma unroll
            for (int reg = 0; reg < 4; reg++) {
                int m = bm + wm + i * 16 + lg * 4 + reg;
                float sq = 0.f;
#pragma unroll
                for (int j = 0; j < 2; j++) {
                    int n = bn + wn + j * 16 + lr;
                    float v = acc[i][j][reg];
                    bool nok = n < D_DIM;
                    if (docost) cst += v * cfp_r[i][reg][j];
                    if (nok) v += bf2f(psi_r[i][reg][j]);
                    else v = 0.f;
                    g.u16[(size_t)m * D_PAD + n] = f2bf(v);
                    sq += v * v;
                }
                sq += __shfl_xor(sq, 1);
                sq += __shfl_xor(sq, 2);
                sq += __shfl_xor(sq, 4);
                sq += __shfl_xor(sq, 8);
                if (lr == 0)
                    g.rowsqP[(size_t)(bx * 2 + (wn >> 5)) * N_TOT + m] = sq;
            }
        }
        if (docost) {
            cst += __shfl_xor(cst, 1); cst += __shfl_xor(cst, 2);
            cst += __shfl_xor(cst, 4); cst += __shfl_xor(cst, 8);
            cst += __shfl_xor(cst, 16); cst += __shfl_xor(cst, 32);
            if (lane == 0) red4[wv] = cst;
            __syncthreads();
            if (t == 0) atomicAdd(g.cost, red4[0] + red4[1] + red4[2] + red4[3]);
        }
    } else if (MODE == 1) {
        __syncthreads();  // stats visibility
#pragma unroll
        for (int i = 0; i < 2; i++) {
#pragma unroll
            for (int reg = 0; reg < 4; reg++) {
                int mi = wm + i * 16 + lg * 4 + reg;
                int m = bm + mi;
                float sm = sclM[mi], am = ahM[mi];
#pragma unroll
                for (int j = 0; j < 2; j++) {
                    int ni = wn + j * 16 + lr;
                    int n = bn + ni;
                    float uv = acc[i][j][reg] * sm * sclN[ni];
                    float kv = __expf(uv - am - ahN[ni]) * uv;
                    size_t idx = (size_t)m * S_ANCH + n;
                    if (!g.finish) {
                        float ab = g.first ? kv : (bf2f(ab_r[i][reg][j]) + 2.0f * kv);
                        g.accb16[idx] = f2bf(ab);
                        float zt = zc_r[i][reg][j] + g.alpha * kv;
                        g.zt16[idx] = f2bf(zt);
                    } else {
                        float z = zc_r[i][reg][j] + g.h6 * (bf2f(ab_r[i][reg][j]) + kv);
                        g.zcur[idx] = z;
                        g.zt16[idx] = f2bf(z);
                        if (m >= S_ANCH)
                            g.outp[(size_t)(m - S_ANCH) * (F_NUM * S_ANCH)
                                   + (size_t)g.tout * S_ANCH + n] = z;
                    }
                }
            }
        }
    } else {
        float s = 0.f;
#pragma unroll
        for (int i = 0; i < 2; i++)
#pragma unroll
            for (int reg = 0; reg < 4; reg++) {
                int m = bm + wm + i * 16 + lg * 4 + reg;
#pragma unroll
                for (int j = 0; j < 2; j++) {
                    int n = bn + wn + j * 16 + lr;
                    if (n < D_DIM) s += acc[i][j][reg] * g.cfp[(size_t)m * D_DIM + n];
                }
            }
        s += __shfl_xor(s, 1); s += __shfl_xor(s, 2); s += __shfl_xor(s, 4);
        s += __shfl_xor(s, 8); s += __shfl_xor(s, 16); s += __shfl_xor(s, 32);
        if (lane == 0) red4[wv] = s;
        __syncthreads();
        if (t == 0) atomicAdd(g.cost, red4[0] + red4[1] + red4[2] + red4[3]);
    }
}

// ---------------- final: add conv_w/b square norm ----------------
__global__ __launch_bounds__(256) void final_kernel(const float* __restrict__ cw,
                                                    const float* __restrict__ cb,
                                                    const float* __restrict__ cost,
                                                    float* __restrict__ out) {
    float s = 0.f;
    for (int i = threadIdx.x; i < 720; i += 256) s += cw[i] * cw[i];
    for (int i = threadIdx.x; i < 80; i += 256) s += cb[i] * cb[i];
    for (int o = 32; o > 0; o >>= 1) s += __shfl_down(s, o);
    __shared__ float red[4];
    if ((threadIdx.x & 63) == 0) red[threadIdx.x >> 6] = s;
    __syncthreads();
    if (threadIdx.x == 0) out[0] = red[0] + red[1] + red[2] + red[3] + cost[0] / 10.0f;
}

// ---------------- host ----------------
extern "C" void kernel_launch(void* const* d_in, const int* in_sizes, int n_in,
                              void* d_out, int out_size, void* d_ws, size_t ws_size,
                              hipStream_t stream) {
    (void)in_sizes; (void)n_in; (void)out_size; (void)ws_size;
    const float* data   = (const float*)d_in[0];
    const float* inputs = (const float*)d_in[1];
    const float* conv_w = (const float*)d_in[2];
    const float* conv_b = (const float*)d_in[3];
    const float* c_s    = (const float*)d_in[4];
    float* out = (float*)d_out;

    char* ws = (char*)d_ws;
    size_t off = 0;
    auto alloc = [&](size_t bytes) {
        char* p = ws + off; off += (bytes + 255) & ~(size_t)255; return p;
    };
    unsigned short* c16T_all = (unsigned short*)alloc((size_t)N_TV * CST * 2);   // 54.8 MB
    float*          cfp_all  = (float*)alloc((size_t)9 * SD * 4);                // 49.8 MB
    unsigned short* psi_all  = (unsigned short*)alloc((size_t)N_TV * PSIP * 2);  // 164.4 MB
    unsigned short* u16      = (unsigned short*)alloc(PSIP * 2);
    float*          z_cur    = (float*)alloc(NS * 4);
    unsigned short* z16      = (unsigned short*)alloc(NS * 2);
    unsigned short* zt16     = (unsigned short*)alloc(NS * 2);
    unsigned short* accb16   = (unsigned short*)alloc(NS * 2);
    float*          rowsqP   = (float*)alloc((size_t)NPART * N_TOT * 4);
    float*          cost     = (float*)alloc(64);

    const double TAU_D = 6.2831853071795864769;
    float ts[F_NUM];
    for (int i = 0; i < F_NUM; i++) ts[i] = (float)((double)i / 9.0);
    W190 Wall;
    for (int j = 0; j < N_TV; j++) {
        float tt;
        if ((j & 1) == 0) tt = ts[j >> 1];
        else {
            int i = j >> 1;
            float h = ts[i + 1] - ts[i];
            tt = ts[i] + 0.5f * h;
        }
        for (int f = 0; f < F_NUM; f++) {
            float coeff = (float)(TAU_D * f);
            float targ = tt * coeff;
            Wall.w[j][f] = (float)cos((double)targ);
        }
    }

    init_kernel<<<2048, 256, 0, stream>>>(z_cur, z16, cost, rowsqP, psi_all, out);
    c_all_kernel<<<dim3(22, 32), 256, 0, stream>>>(c_s, c16T_all, cfp_all, Wall);
    const int conv_blocks = (int)(((size_t)N_TOT * 8 * 169 + 255) / 256);
    conv_psi_all_kernel<<<conv_blocks, 256, 0, stream>>>(data, inputs, conv_w, conv_b,
                                                         psi_all, Wall);

    GemmArgs g0 = {}; // GEMM1: u = z@cT + psi (+ fused cost at e=0)
    g0.lda = S_ANCH; g0.ldb = S_ANCH; g0.K = S_ANCH; g0.gx = 22;
    g0.u16 = u16; g0.rowsqP = rowsqP; g0.cost = cost;
    GemmArgs g1 = {}; // GEMM2: kernel + RK4 bookkeeping
    g1.lda = D_PAD; g1.ldb = D_PAD; g1.K = D_K; g1.gx = 16;
    g1.zcur = z_cur; g1.accb16 = accb16; g1.rowsqP = rowsqP;
    GemmArgs g2 = {}; // final cost quadratic form (t_9)
    g2.A = z16; g2.B = c16T_all + (size_t)18 * CST;
    g2.lda = S_ANCH; g2.ldb = S_ANCH; g2.K = S_ANCH; g2.gx = 22;
    g2.cfp = cfp_all + (size_t)8 * SD; g2.cost = cost;

    for (int i = 0; i < 9; i++) {
        float h = ts[i + 1] - ts[i];
        int js[4] = {2 * i, 2 * i + 1, 2 * i + 1, 2 * i + 2};
        float alphas[3] = {0.5f * h, 0.5f * h, h};
        for (int e = 0; e < 4; e++) {
            int j = js[e];
            const bool shortcut = (i == 0 && e == 0);   // z == 0 -> u == psi
            if (shortcut) {
                rowsq_psi_kernel<<<N_TOT / 4, 256, 0, stream>>>(psi_all, rowsqP);
            } else {
                g0.A = (e == 0) ? z16 : zt16;
                g0.B = c16T_all + (size_t)j * CST;
                g0.psi16 = psi_all + (size_t)j * PSIP;
                g0.do_cost = (e == 0 && i >= 1) ? 1 : 0;
                g0.cfp = (i >= 1) ? (cfp_all + (size_t)(i - 1) * SD) : cfp_all;
                mfma_gemm<0><<<22 * 48, 256, 0, stream>>>(g0);
            }
            g1.A = shortcut ? psi_all : u16;
            g1.B = shortcut ? psi_all : u16;
            g1.first = (e == 0); g1.finish = (e == 3);
            g1.alpha = (e < 3) ? alphas[e] : 0.f;
            g1.h6 = h / 6.0f; g1.tout = i + 1;
            g1.zt16 = (e < 3) ? zt16 : z16;
            g1.outp = out;
            mfma_gemm<1><<<16 * 48, 256, 0, stream>>>(g1);
        }
    }
    // cost contribution at t_9 (z16 holds z_{t9})
    mfma_gemm<2><<<22 * 16, 256, 0, stream>>>(g2);

    final_kernel<<<1, 256, 0, stream>>>(conv_w, conv_b, cost, out + OUT_Z);
}

// Round 17
// 2048.544 us; speedup vs baseline: 2.7774x; 1.0981x over previous
//
#include <hip/hip_runtime.h>
#include <hip/hip_fp8.h>
#include <math.h>

#define S_ANCH 1024
#define B_QRY  2048
#define N_TOT  3072
#define D_DIM  1352
#define D_PAD  1408   // padded D: u8/psi stride (elements), c16T rows
#define F_NUM  10
#define N_TV   19
#define NPART  44     // 22 n-tiles * 2 wave-halves in GEMM1

static const size_t SD    = (size_t)S_ANCH * D_DIM;
static const size_t NS    = (size_t)N_TOT * S_ANCH;
static const size_t CST   = (size_t)D_PAD * S_ANCH;   // one c16T plane
static const size_t PSIP  = (size_t)N_TOT * D_PAD;    // one psi plane (elements)
static const size_t OUT_Z = (size_t)B_QRY * F_NUM * S_ANCH;

typedef __attribute__((ext_vector_type(8))) short bf16x8;
typedef __attribute__((ext_vector_type(4))) float f32x4;

struct W190 { float w[N_TV][F_NUM]; };

__device__ inline unsigned short f2bf(float x) {
    unsigned int u = __builtin_bit_cast(unsigned int, x);
    unsigned int r = (u + 0x7FFFu + ((u >> 16) & 1u)) >> 16;
    return (unsigned short)r;
}
__device__ inline float bf2f(unsigned short v) {
    unsigned int u = ((unsigned int)v) << 16;
    return __builtin_bit_cast(float, u);
}
__device__ inline unsigned char f2fp8(float x) {
    __hip_fp8_e4m3 q(x);            // OCP e4m3fn on gfx950, saturating
    return (unsigned char)q.__x;
}

__device__ __forceinline__ void stage16(const unsigned char* gp, unsigned char* lp) {
    __builtin_amdgcn_global_load_lds(
        (const __attribute__((address_space(1))) unsigned int*)(const void*)gp,
        (__attribute__((address_space(3))) unsigned int*)(void*)lp, 16, 0, 0);
}

// ------- init: zero z, z16, cost, rowsqP, psi-plane0 pad, t=0 out slice -------
__global__ __launch_bounds__(256) void init_kernel(float* __restrict__ z,
                                                   unsigned short* __restrict__ z16,
                                                   float* __restrict__ cost,
                                                   float* __restrict__ rowsqP,
                                                   unsigned short* __restrict__ psi0,
                                                   float* __restrict__ out) {
    size_t idx = (size_t)blockIdx.x * blockDim.x + threadIdx.x;
    size_t stride = (size_t)gridDim.x * blockDim.x;
    for (size_t i = idx; i < NS; i += stride) { z[i] = 0.f; z16[i] = 0; }
    const size_t NO = (size_t)B_QRY * S_ANCH;
    for (size_t i = idx; i < NO; i += stride) {
        size_t b = i >> 10, s = i & 1023;
        out[b * (size_t)(F_NUM * S_ANCH) + s] = 0.f;
    }
    const size_t NR = (size_t)NPART * N_TOT;
    for (size_t i = idx; i < NR; i += stride) rowsqP[i] = 0.f;
    const size_t NPAD = (size_t)N_TOT * (D_PAD - D_DIM);
    for (size_t i = idx; i < NPAD; i += stride) {
        size_t n = i / (D_PAD - D_DIM), c = i % (D_PAD - D_DIM);
        psi0[n * D_PAD + D_DIM + c] = 0;
    }
    if (idx == 0) cost[0] = 0.f;
}

// ---------------- ALL c_t planes in one pass over c_s ----------------
__global__ __launch_bounds__(256) void c_all_kernel(const float* __restrict__ cs,
                                                    unsigned short* __restrict__ cT,
                                                    float* __restrict__ cfp, W190 W) {
    __shared__ float tile[32][65];
    int d0 = blockIdx.x * 64, s0 = blockIdx.y * 32;
    int t = threadIdx.x;
    int d_l = t & 63, s_base = t >> 6;
    int d = d0 + d_l;
    bool dok = (d < D_DIM);
    float creg[8][F_NUM];
#pragma unroll
    for (int it = 0; it < 8; it++) {
        int s = s0 + s_base + it * 4;
        const float* p = cs + ((size_t)s * D_DIM + d) * F_NUM;
#pragma unroll
        for (int f = 0; f < F_NUM; f++) creg[it][f] = dok ? p[f] : 0.f;
    }
    for (int j = 0; j < N_TV; j++) {
        float v[8];
#pragma unroll
        for (int it = 0; it < 8; it++) {
            float s = 0.f;
#pragma unroll
            for (int f = 0; f < F_NUM; f++) s += creg[it][f] * W.w[j][f];
            v[it] = s;
            tile[s_base + it * 4][d_l] = s;
        }
        if ((j & 1) == 0 && j >= 2 && dok) {
            int gi = (j >> 1) - 1;
#pragma unroll
            for (int it = 0; it < 8; it++)
                cfp[(size_t)gi * SD + (size_t)(s0 + s_base + it * 4) * D_DIM + d] = v[it];
        }
        __syncthreads();
        int s_l = t & 31, dr = t >> 5;
#pragma unroll
        for (int p8 = 0; p8 < 8; p8++) {
            int dd = dr + p8 * 8;
            cT[(size_t)j * CST + (size_t)(d0 + dd) * S_ANCH + s0 + s_l] = f2bf(tile[s_l][dd]);
        }
        __syncthreads();
    }
}

// ---------------- ALL psi_t planes: conv once, 19 freq-dots ----------------
__global__ __launch_bounds__(256) void conv_psi_all_kernel(const float* __restrict__ data,
                                                           const float* __restrict__ inputs,
                                                           const float* __restrict__ cw,
                                                           const float* __restrict__ cb,
                                                           unsigned short* __restrict__ psi_all,
                                                           W190 W) {
    __shared__ float wsh[720];
    __shared__ float bsh[80];
    for (int i = threadIdx.x; i < 720; i += 256) wsh[i] = cw[i];
    for (int i = threadIdx.x; i < 80; i += 256) bsh[i] = cb[i];
    __syncthreads();
    size_t idx = (size_t)blockIdx.x * 256 + threadIdx.x;
    if (idx >= (size_t)N_TOT * 8 * 169) return;
    int pos = (int)(idx % 169);
    int rest = (int)(idx / 169);
    int c8 = rest & 7;
    int n = rest >> 3;
    int oi = pos / 13, oj = pos % 13;
    const float* x = (n < S_ANCH) ? (data + (size_t)n * 784)
                                  : (inputs + (size_t)(n - S_ANCH) * 784);
    float vin[9];
#pragma unroll
    for (int kh = 0; kh < 3; kh++)
#pragma unroll
        for (int kw = 0; kw < 3; kw++)
            vin[kh * 3 + kw] = x[(2 * oi + kh) * 28 + (2 * oj + kw)];
    float s[F_NUM];
#pragma unroll
    for (int f = 0; f < F_NUM; f++) {
        int co = f * 8 + c8;
        float acc = bsh[co];
#pragma unroll
        for (int t = 0; t < 9; t++) acc += vin[t] * wsh[co * 9 + t];
        s[f] = acc;
    }
    size_t base = (size_t)n * D_PAD + c8 * 169 + pos;
#pragma unroll
    for (int j = 0; j < N_TV; j++) {
        float p = 0.f;
#pragma unroll
        for (int f = 0; f < F_NUM; f++) p += s[f] * W.w[j][f];
        psi_all[(size_t)j * PSIP + base] = f2bf(p);
    }
}

// -- rowsq of psi plane 0 + u8 = fp8(psi0) (t=0 shortcut: u == psi) --
__global__ __launch_bounds__(256) void rowsq_psi_kernel(const unsigned short* __restrict__ psi0,
                                                        float* __restrict__ rowsqP,
                                                        unsigned char* __restrict__ u8) {
    int wv = threadIdx.x >> 6, lane = threadIdx.x & 63;
    int r = blockIdx.x * 4 + wv;
    const unsigned short* row = psi0 + (size_t)r * D_PAD;
    unsigned char* orow = u8 + (size_t)r * D_PAD;
    float s = 0.f;
    for (int c = lane; c < D_PAD / 8; c += 64) {
        int4 v = *(const int4*)(row + c * 8);
        const unsigned short* u = (const unsigned short*)&v;
        unsigned long long w = 0ull;
#pragma unroll
        for (int e = 0; e < 8; e++) {
            float f = bf2f(u[e]);
            s += f * f;
            w |= (unsigned long long)f2fp8(f) << (8 * e);
        }
        *(unsigned long long*)(orow + c * 8) = w;
    }
    s += __shfl_xor(s, 1); s += __shfl_xor(s, 2); s += __shfl_xor(s, 4);
    s += __shfl_xor(s, 8); s += __shfl_xor(s, 16); s += __shfl_xor(s, 32);
    if (lane == 0) rowsqP[r] = s;   // slot 0; slots 1..43 zeroed by init
}

// ---- MFMA GEMM (NT), 64x64 tile, 64B K-step, 6-buf depth-5 counted-vmcnt ----
// MODE 0/2: bf16 operands (K-step = 32 bf16). MODE 1: fp8 operands (K-step = 64 fp8).
// Byte-identical LDS/staging layout; T14 epilogue-input prefetch throughout.
struct GemmArgs {
    const unsigned char* A; const unsigned char* B;
    int lda, ldb, K;        // BYTES
    int gx;
    // MODE 0
    const unsigned short* psi16; unsigned char* u8; float* rowsqP;
    int do_cost;
    // MODE 0 (cost fusion) + MODE 2
    const float* cfp; float* cost;
    // MODE 1
    float* zcur; unsigned short* accb16; unsigned short* zt16; float* outp;
    int first, finish, tout; float alpha, h6;
};

template<int MODE>
__global__ __launch_bounds__(256) void mfma_gemm(GemmArgs g) {
    __shared__ __align__(16) unsigned char As[6][64][64];
    __shared__ __align__(16) unsigned char Bs[6][64][64];
    __shared__ float sclM[64], ahM[64], sclN[64], ahN[64];
    __shared__ float red4[4];
    const int nb = gridDim.x;
    const int lin = blockIdx.x;
    const int swz = (lin & 7) * (nb >> 3) + (lin >> 3);
    const int bx = swz % g.gx, by = swz / g.gx;
    const int bm = by * 64, bn = bx * 64;
    const int t = threadIdx.x;
    const int lane = t & 63, wv = t >> 6;
    const int wm = (wv >> 1) * 32, wn = (wv & 1) * 32;
    const int lr = lane & 15, lg = lane >> 4;
    const int srow = lane >> 2;
    const int gch = (lane & 3) ^ ((lane >> 3) & 3);
    const int sl = lg ^ ((lr >> 1) & 3);

    if (MODE == 1) {
        if (t < 128) {
            int r = (t < 64) ? (bm + t) : (bn + (t - 64));
            float tot = 0.f;
#pragma unroll
            for (int c = 0; c < NPART; c++) tot += g.rowsqP[(size_t)c * N_TOT + r];
            float norm = sqrtf(tot + 1e-6f);
            float sg = 1.f / (1.f + __expf(-norm));
            float sc = sg / norm;
            float a = 0.5f * tot * sc * sc;
            if (t < 64) { sclM[t] = sc; ahM[t] = a; }
            else        { sclN[t - 64] = sc; ahN[t - 64] = a; }
        }
    }

    // ---- T14: early epilogue-input loads (independent of MFMA results) ----
    const bool docost = (MODE == 0) && g.do_cost && (bm < S_ANCH);
    unsigned short psi_r[2][4][2];
    float cfp_r[2][4][2];
    float zc_r[2][4][2];
    unsigned short ab_r[2][4][2];
    if (MODE == 0) {
#pragma unroll
        for (int i = 0; i < 2; i++)
#pragma unroll
            for (int reg = 0; reg < 4; reg++) {
                int m = bm + wm + i * 16 + lg * 4 + reg;
#pragma unroll
                for (int j = 0; j < 2; j++) {
                    int n = bn + wn + j * 16 + lr;
                    psi_r[i][reg][j] = g.psi16[(size_t)m * D_PAD + n];
                    if (docost)
                        cfp_r[i][reg][j] = (n < D_DIM) ? g.cfp[(size_t)m * D_DIM + n] : 0.f;
                }
            }
    } else if (MODE == 1) {
#pragma unroll
        for (int i = 0; i < 2; i++)
#pragma unroll
            for (int reg = 0; reg < 4; reg++) {
                int m = bm + wm + i * 16 + lg * 4 + reg;
#pragma unroll
                for (int j = 0; j < 2; j++) {
                    int n = bn + wn + j * 16 + lr;
                    size_t idx = (size_t)m * S_ANCH + n;
                    zc_r[i][reg][j] = g.zcur[idx];
                    ab_r[i][reg][j] = g.accb16[idx];
                }
            }
    }
    __builtin_amdgcn_sched_barrier(0);   // pin early loads before staging

    f32x4 acc[2][2];
#pragma unroll
    for (int i = 0; i < 2; i++)
#pragma unroll
        for (int j = 0; j < 2; j++) acc[i][j] = (f32x4){0.f, 0.f, 0.f, 0.f};

    const unsigned char* Abase = g.A + (size_t)(bm + wv * 16 + srow) * g.lda + gch * 16;
    const unsigned char* Bbase = g.B + (size_t)(bn + wv * 16 + srow) * g.ldb + gch * 16;

    auto STAGE = [&](int k) {
        int buf = k % 6;
        stage16(Abase + (k << 6), &As[buf][wv * 16][0]);
        stage16(Bbase + (k << 6), &Bs[buf][wv * 16][0]);
    };
    auto COMPUTE = [&](int k) {
        int buf = k % 6;
        if (MODE != 1) {
            bf16x8 af[2], bf[2];
#pragma unroll
            for (int i = 0; i < 2; i++)
                af[i] = *(const bf16x8*)&As[buf][wm + i * 16 + lr][sl * 16];
#pragma unroll
            for (int j = 0; j < 2; j++)
                bf[j] = *(const bf16x8*)&Bs[buf][wn + j * 16 + lr][sl * 16];
#pragma unroll
            for (int i = 0; i < 2; i++)
#pragma unroll
                for (int j = 0; j < 2; j++)
                    acc[i][j] = __builtin_amdgcn_mfma_f32_16x16x32_bf16(af[i], bf[j], acc[i][j], 0, 0, 0);
        } else {
#pragma unroll
            for (int ks = 0; ks < 2; ks++) {
                int ch = ((ks << 1) + (lg >> 1)) ^ ((lr >> 1) & 3);
                int off = ch * 16 + (lg & 1) * 8;
                long a0 = *(const long*)&As[buf][wm + lr][off];
                long a1 = *(const long*)&As[buf][wm + 16 + lr][off];
                long b0 = *(const long*)&Bs[buf][wn + lr][off];
                long b1 = *(const long*)&Bs[buf][wn + 16 + lr][off];
                acc[0][0] = __builtin_amdgcn_mfma_f32_16x16x32_fp8_fp8(a0, b0, acc[0][0], 0, 0, 0);
                acc[0][1] = __builtin_amdgcn_mfma_f32_16x16x32_fp8_fp8(a0, b1, acc[0][1], 0, 0, 0);
                acc[1][0] = __builtin_amdgcn_mfma_f32_16x16x32_fp8_fp8(a1, b0, acc[1][0], 0, 0, 0);
                acc[1][1] = __builtin_amdgcn_mfma_f32_16x16x32_fp8_fp8(a1, b1, acc[1][1], 0, 0, 0);
            }
        }
    };

    const int nt = g.K >> 6;   // 32 (bf16 K=1024) or 22 (fp8 K=1408); always > 6
    STAGE(0); STAGE(1); STAGE(2); STAGE(3); STAGE(4);
    for (int k = 0; k < nt - 5; ++k) {
        asm volatile("s_waitcnt vmcnt(8)" ::: "memory");
        __builtin_amdgcn_s_barrier();
        __builtin_amdgcn_sched_barrier(0);
        STAGE(k + 5);
        COMPUTE(k);
    }
    asm volatile("s_waitcnt vmcnt(8)" ::: "memory");
    __builtin_amdgcn_s_barrier(); __builtin_amdgcn_sched_barrier(0);
    COMPUTE(nt - 5);
    asm volatile("s_waitcnt vmcnt(6)" ::: "memory");
    __builtin_amdgcn_s_barrier(); __builtin_amdgcn_sched_barrier(0);
    COMPUTE(nt - 4);
    asm volatile("s_waitcnt vmcnt(4)" ::: "memory");
    __builtin_amdgcn_s_barrier(); __builtin_amdgcn_sched_barrier(0);
    COMPUTE(nt - 3);
    asm volatile("s_waitcnt vmcnt(2)" ::: "memory");
    __builtin_amdgcn_s_barrier(); __builtin_amdgcn_sched_barrier(0);
    COMPUTE(nt - 2);
    asm volatile("s_waitcnt vmcnt(0)" ::: "memory");
    __builtin_amdgcn_s_barrier(); __builtin_amdgcn_sched_barrier(0);
    COMPUTE(nt - 1);

    // ---------------- epilogues (inputs already in registers) ----------------
    if (MODE == 0) {
        float cst = 0.f;
#pragma unroll
        for (int i = 0; i < 2; i++) {
#pragma unroll
            for (int reg = 0; reg < 4; reg++) {
                int m = bm + wm + i * 16 + lg * 4 + reg;
                float sq = 0.f;
#pragma unroll
                for (int j = 0; j < 2; j++) {
                    int n = bn + wn + j * 16 + lr;
                    float v = acc[i][j][reg];
                    bool nok = n < D_DIM;
                    if (docost) cst += v * cfp_r[i][reg][j];
                    if (nok) v += bf2f(psi_r[i][reg][j]);
                    else v = 0.f;
                    g.u8[(size_t)m * D_PAD + n] = f2fp8(v);
                    sq += v * v;
                }
                sq += __shfl_xor(sq, 1);
                sq += __shfl_xor(sq, 2);
                sq += __shfl_xor(sq, 4);
                sq += __shfl_xor(sq, 8);
                if (lr == 0)
                    g.rowsqP[(size_t)(bx * 2 + (wn >> 5)) * N_TOT + m] = sq;
            }
        }
        if (docost) {
            cst += __shfl_xor(cst, 1); cst += __shfl_xor(cst, 2);
            cst += __shfl_xor(cst, 4); cst += __shfl_xor(cst, 8);
            cst += __shfl_xor(cst, 16); cst += __shfl_xor(cst, 32);
            if (lane == 0) red4[wv] = cst;
            __syncthreads();
            if (t == 0) atomicAdd(g.cost, red4[0] + red4[1] + red4[2] + red4[3]);
        }
    } else if (MODE == 1) {
        __syncthreads();  // stats visibility
#pragma unroll
        for (int i = 0; i < 2; i++) {
#pragma unroll
            for (int reg = 0; reg < 4; reg++) {
                int mi = wm + i * 16 + lg * 4 + reg;
                int m = bm + mi;
                float sm = sclM[mi], am = ahM[mi];
#pragma unroll
                for (int j = 0; j < 2; j++) {
                    int ni = wn + j * 16 + lr;
                    int n = bn + ni;
                    float uv = acc[i][j][reg] * sm * sclN[ni];
                    float kv = __expf(uv - am - ahN[ni]) * uv;
                    size_t idx = (size_t)m * S_ANCH + n;
                    if (!g.finish) {
                        float ab = g.first ? kv : (bf2f(ab_r[i][reg][j]) + 2.0f * kv);
                        g.accb16[idx] = f2bf(ab);
                        float zt = zc_r[i][reg][j] + g.alpha * kv;
                        g.zt16[idx] = f2bf(zt);
                    } else {
                        float z = zc_r[i][reg][j] + g.h6 * (bf2f(ab_r[i][reg][j]) + kv);
                        g.zcur[idx] = z;
                        g.zt16[idx] = f2bf(z);
                        if (m >= S_ANCH)
                            g.outp[(size_t)(m - S_ANCH) * (F_NUM * S_ANCH)
                                   + (size_t)g.tout * S_ANCH + n] = z;
                    }
                }
            }
        }
    } else {
        float s = 0.f;
#pragma unroll
        for (int i = 0; i < 2; i++)
#pragma unroll
            for (int reg = 0; reg < 4; reg++) {
                int m = bm + wm + i * 16 + lg * 4 + reg;
#pragma unroll
                for (int j = 0; j < 2; j++) {
                    int n = bn + wn + j * 16 + lr;
                    if (n < D_DIM) s += acc[i][j][reg] * g.cfp[(size_t)m * D_DIM + n];
                }
            }
        s += __shfl_xor(s, 1); s += __shfl_xor(s, 2); s += __shfl_xor(s, 4);
        s += __shfl_xor(s, 8); s += __shfl_xor(s, 16); s += __shfl_xor(s, 32);
        if (lane == 0) red4[wv] = s;
        __syncthreads();
        if (t == 0) atomicAdd(g.cost, red4[0] + red4[1] + red4[2] + red4[3]);
    }
}

// ---------------- final: add conv_w/b square norm ----------------
__global__ __launch_bounds__(256) void final_kernel(const float* __restrict__ cw,
                                                    const float* __restrict__ cb,
                                                    const float* __restrict__ cost,
                                                    float* __restrict__ out) {
    float s = 0.f;
    for (int i = threadIdx.x; i < 720; i += 256) s += cw[i] * cw[i];
    for (int i = threadIdx.x; i < 80; i += 256) s += cb[i] * cb[i];
    for (int o = 32; o > 0; o >>= 1) s += __shfl_down(s, o);
    __shared__ float red[4];
    if ((threadIdx.x & 63) == 0) red[threadIdx.x >> 6] = s;
    __syncthreads();
    if (threadIdx.x == 0) out[0] = red[0] + red[1] + red[2] + red[3] + cost[0] / 10.0f;
}

// ---------------- host ----------------
extern "C" void kernel_launch(void* const* d_in, const int* in_sizes, int n_in,
                              void* d_out, int out_size, void* d_ws, size_t ws_size,
                              hipStream_t stream) {
    (void)in_sizes; (void)n_in; (void)out_size; (void)ws_size;
    const float* data   = (const float*)d_in[0];
    const float* inputs = (const float*)d_in[1];
    const float* conv_w = (const float*)d_in[2];
    const float* conv_b = (const float*)d_in[3];
    const float* c_s    = (const float*)d_in[4];
    float* out = (float*)d_out;

    char* ws = (char*)d_ws;
    size_t off = 0;
    auto alloc = [&](size_t bytes) {
        char* p = ws + off; off += (bytes + 255) & ~(size_t)255; return p;
    };
    unsigned short* c16T_all = (unsigned short*)alloc((size_t)N_TV * CST * 2);   // 54.8 MB
    float*          cfp_all  = (float*)alloc((size_t)9 * SD * 4);                // 49.8 MB
    unsigned short* psi_all  = (unsigned short*)alloc((size_t)N_TV * PSIP * 2);  // 164.4 MB
    unsigned char*  u8       = (unsigned char*)alloc(PSIP);                      // 4.3 MB
    float*          z_cur    = (float*)alloc(NS * 4);
    unsigned short* z16      = (unsigned short*)alloc(NS * 2);
    unsigned short* zt16     = (unsigned short*)alloc(NS * 2);
    unsigned short* accb16   = (unsigned short*)alloc(NS * 2);
    float*          rowsqP   = (float*)alloc((size_t)NPART * N_TOT * 4);
    float*          cost     = (float*)alloc(64);

    const double TAU_D = 6.2831853071795864769;
    float ts[F_NUM];
    for (int i = 0; i < F_NUM; i++) ts[i] = (float)((double)i / 9.0);
    W190 Wall;
    for (int j = 0; j < N_TV; j++) {
        float tt;
        if ((j & 1) == 0) tt = ts[j >> 1];
        else {
            int i = j >> 1;
            float h = ts[i + 1] - ts[i];
            tt = ts[i] + 0.5f * h;
        }
        for (int f = 0; f < F_NUM; f++) {
            float coeff = (float)(TAU_D * f);
            float targ = tt * coeff;
            Wall.w[j][f] = (float)cos((double)targ);
        }
    }

    init_kernel<<<2048, 256, 0, stream>>>(z_cur, z16, cost, rowsqP, psi_all, out);
    c_all_kernel<<<dim3(22, 32), 256, 0, stream>>>(c_s, c16T_all, cfp_all, Wall);
    const int conv_blocks = (int)(((size_t)N_TOT * 8 * 169 + 255) / 256);
    conv_psi_all_kernel<<<conv_blocks, 256, 0, stream>>>(data, inputs, conv_w, conv_b,
                                                         psi_all, Wall);

    GemmArgs g0 = {}; // GEMM1 (bf16): u = z@cT + psi (+ fused cost at e=0) -> u8
    g0.lda = S_ANCH * 2; g0.ldb = S_ANCH * 2; g0.K = S_ANCH * 2; g0.gx = 22;
    g0.u8 = u8; g0.rowsqP = rowsqP; g0.cost = cost;
    GemmArgs g1 = {}; // GEMM2 (fp8): kernel + RK4 bookkeeping
    g1.A = u8; g1.B = u8; g1.lda = D_PAD; g1.ldb = D_PAD; g1.K = D_PAD; g1.gx = 16;
    g1.zcur = z_cur; g1.accb16 = accb16; g1.rowsqP = rowsqP;
    GemmArgs g2 = {}; // final cost quadratic form (bf16, t_9)
    g2.A = (const unsigned char*)z16;
    g2.B = (const unsigned char*)(c16T_all + (size_t)18 * CST);
    g2.lda = S_ANCH * 2; g2.ldb = S_ANCH * 2; g2.K = S_ANCH * 2; g2.gx = 22;
    g2.cfp = cfp_all + (size_t)8 * SD; g2.cost = cost;

    for (int i = 0; i < 9; i++) {
        float h = ts[i + 1] - ts[i];
        int js[4] = {2 * i, 2 * i + 1, 2 * i + 1, 2 * i + 2};
        float alphas[3] = {0.5f * h, 0.5f * h, h};
        for (int e = 0; e < 4; e++) {
            int j = js[e];
            const bool shortcut = (i == 0 && e == 0);   // z == 0 -> u == psi
            if (shortcut) {
                rowsq_psi_kernel<<<N_TOT / 4, 256, 0, stream>>>(psi_all, rowsqP, u8);
            } else {
                g0.A = (const unsigned char*)((e == 0) ? z16 : zt16);
                g0.B = (const unsigned char*)(c16T_all + (size_t)j * CST);
                g0.psi16 = psi_all + (size_t)j * PSIP;
                g0.do_cost = (e == 0 && i >= 1) ? 1 : 0;
                g0.cfp = (i >= 1) ? (cfp_all + (size_t)(i - 1) * SD) : cfp_all;
                mfma_gemm<0><<<22 * 48, 256, 0, stream>>>(g0);
            }
            g1.first = (e == 0); g1.finish = (e == 3);
            g1.alpha = (e < 3) ? alphas[e] : 0.f;
            g1.h6 = h / 6.0f; g1.tout = i + 1;
            g1.zt16 = (e < 3) ? zt16 : z16;
            g1.outp = out;
            mfma_gemm<1><<<16 * 48, 256, 0, stream>>>(g1);
        }
    }
    // cost contribution at t_9 (z16 holds z_{t9})
    mfma_gemm<2><<<22 * 16, 256, 0, stream>>>(g2);

    final_kernel<<<1, 256, 0, stream>>>(conv_w, conv_b, cost, out + OUT_Z);
}

// Round 18
// 1674.635 us; speedup vs baseline: 3.3975x; 1.2233x over previous
//
#include <hip/hip_runtime.h>
#include <hip/hip_fp8.h>
#include <math.h>

#define S_ANCH 1024
#define B_QRY  2048
#define N_TOT  3072
#define D_DIM  1352
#define D_PAD  1408   // padded D: u8/psi stride (elements), c8 rows
#define F_NUM  10
#define N_TV   19
#define NPART  44     // 22 n-tiles * 2 wave-halves in GEMM1
#define CSCALE 128.0f
#define CINV   (1.0f / 128.0f)

static const size_t SD    = (size_t)S_ANCH * D_DIM;
static const size_t NS    = (size_t)N_TOT * S_ANCH;
static const size_t CST   = (size_t)D_PAD * S_ANCH;   // one c8 plane (bytes)
static const size_t PSIP  = (size_t)N_TOT * D_PAD;    // one psi plane (elements)
static const size_t OUT_Z = (size_t)B_QRY * F_NUM * S_ANCH;

typedef __attribute__((ext_vector_type(8))) short bf16x8;
typedef __attribute__((ext_vector_type(4))) float f32x4;

struct W190 { float w[N_TV][F_NUM]; };

__device__ inline unsigned short f2bf(float x) {
    unsigned int u = __builtin_bit_cast(unsigned int, x);
    unsigned int r = (u + 0x7FFFu + ((u >> 16) & 1u)) >> 16;
    return (unsigned short)r;
}
__device__ inline float bf2f(unsigned short v) {
    unsigned int u = ((unsigned int)v) << 16;
    return __builtin_bit_cast(float, u);
}
__device__ inline unsigned char f2fp8(float x) {
    __hip_fp8_e4m3 q(x);            // OCP e4m3fn on gfx950, saturating
    return (unsigned char)q.__x;
}

__device__ __forceinline__ void stage16(const unsigned char* gp, unsigned char* lp) {
    __builtin_amdgcn_global_load_lds(
        (const __attribute__((address_space(1))) unsigned int*)(const void*)gp,
        (__attribute__((address_space(3))) unsigned int*)(void*)lp, 16, 0, 0);
}

// ------- init: zero z, z8, cost, rowsqP, psi-plane0 pad, t=0 out slice -------
__global__ __launch_bounds__(256) void init_kernel(float* __restrict__ z,
                                                   unsigned char* __restrict__ z8,
                                                   float* __restrict__ cost,
                                                   float* __restrict__ rowsqP,
                                                   unsigned short* __restrict__ psi0,
                                                   float* __restrict__ out) {
    size_t idx = (size_t)blockIdx.x * blockDim.x + threadIdx.x;
    size_t stride = (size_t)gridDim.x * blockDim.x;
    for (size_t i = idx; i < NS; i += stride) { z[i] = 0.f; z8[i] = 0; }
    const size_t NO = (size_t)B_QRY * S_ANCH;
    for (size_t i = idx; i < NO; i += stride) {
        size_t b = i >> 10, s = i & 1023;
        out[b * (size_t)(F_NUM * S_ANCH) + s] = 0.f;
    }
    const size_t NR = (size_t)NPART * N_TOT;
    for (size_t i = idx; i < NR; i += stride) rowsqP[i] = 0.f;
    const size_t NPAD = (size_t)N_TOT * (D_PAD - D_DIM);
    for (size_t i = idx; i < NPAD; i += stride) {
        size_t n = i / (D_PAD - D_DIM), c = i % (D_PAD - D_DIM);
        psi0[n * D_PAD + D_DIM + c] = 0;
    }
    if (idx == 0) cost[0] = 0.f;
}

// ------- ALL c_t planes in one pass: fp8(c*128) transposed + fp32 cost planes -------
__global__ __launch_bounds__(256) void c_all_kernel(const float* __restrict__ cs,
                                                    unsigned char* __restrict__ c8,
                                                    float* __restrict__ cfp, W190 W) {
    __shared__ float tile[32][65];
    int d0 = blockIdx.x * 64, s0 = blockIdx.y * 32;
    int t = threadIdx.x;
    int d_l = t & 63, s_base = t >> 6;
    int d = d0 + d_l;
    bool dok = (d < D_DIM);
    float creg[8][F_NUM];
#pragma unroll
    for (int it = 0; it < 8; it++) {
        int s = s0 + s_base + it * 4;
        const float* p = cs + ((size_t)s * D_DIM + d) * F_NUM;
#pragma unroll
        for (int f = 0; f < F_NUM; f++) creg[it][f] = dok ? p[f] : 0.f;
    }
    for (int j = 0; j < N_TV; j++) {
        float v[8];
#pragma unroll
        for (int it = 0; it < 8; it++) {
            float s = 0.f;
#pragma unroll
            for (int f = 0; f < F_NUM; f++) s += creg[it][f] * W.w[j][f];
            v[it] = s;
            tile[s_base + it * 4][d_l] = s;
        }
        if ((j & 1) == 0 && j >= 2 && dok) {
            int gi = (j >> 1) - 1;
#pragma unroll
            for (int it = 0; it < 8; it++)
                cfp[(size_t)gi * SD + (size_t)(s0 + s_base + it * 4) * D_DIM + d] = v[it];
        }
        __syncthreads();
        int s_l = t & 31, dr = t >> 5;
#pragma unroll
        for (int p8 = 0; p8 < 8; p8++) {
            int dd = dr + p8 * 8;
            c8[(size_t)j * CST + (size_t)(d0 + dd) * S_ANCH + s0 + s_l] =
                f2fp8(tile[s_l][dd] * CSCALE);
        }
        __syncthreads();
    }
}

// ---------------- ALL psi_t planes: conv once, 19 freq-dots ----------------
__global__ __launch_bounds__(256) void conv_psi_all_kernel(const float* __restrict__ data,
                                                           const float* __restrict__ inputs,
                                                           const float* __restrict__ cw,
                                                           const float* __restrict__ cb,
                                                           unsigned short* __restrict__ psi_all,
                                                           W190 W) {
    __shared__ float wsh[720];
    __shared__ float bsh[80];
    for (int i = threadIdx.x; i < 720; i += 256) wsh[i] = cw[i];
    for (int i = threadIdx.x; i < 80; i += 256) bsh[i] = cb[i];
    __syncthreads();
    size_t idx = (size_t)blockIdx.x * 256 + threadIdx.x;
    if (idx >= (size_t)N_TOT * 8 * 169) return;
    int pos = (int)(idx % 169);
    int rest = (int)(idx / 169);
    int c8 = rest & 7;
    int n = rest >> 3;
    int oi = pos / 13, oj = pos % 13;
    const float* x = (n < S_ANCH) ? (data + (size_t)n * 784)
                                  : (inputs + (size_t)(n - S_ANCH) * 784);
    float vin[9];
#pragma unroll
    for (int kh = 0; kh < 3; kh++)
#pragma unroll
        for (int kw = 0; kw < 3; kw++)
            vin[kh * 3 + kw] = x[(2 * oi + kh) * 28 + (2 * oj + kw)];
    float s[F_NUM];
#pragma unroll
    for (int f = 0; f < F_NUM; f++) {
        int co = f * 8 + c8;
        float acc = bsh[co];
#pragma unroll
        for (int t = 0; t < 9; t++) acc += vin[t] * wsh[co * 9 + t];
        s[f] = acc;
    }
    size_t base = (size_t)n * D_PAD + c8 * 169 + pos;
#pragma unroll
    for (int j = 0; j < N_TV; j++) {
        float p = 0.f;
#pragma unroll
        for (int f = 0; f < F_NUM; f++) p += s[f] * W.w[j][f];
        psi_all[(size_t)j * PSIP + base] = f2bf(p);
    }
}

// -- rowsq of psi plane 0 + u8 = fp8(psi0) (t=0 shortcut: u == psi) --
__global__ __launch_bounds__(256) void rowsq_psi_kernel(const unsigned short* __restrict__ psi0,
                                                        float* __restrict__ rowsqP,
                                                        unsigned char* __restrict__ u8) {
    int wv = threadIdx.x >> 6, lane = threadIdx.x & 63;
    int r = blockIdx.x * 4 + wv;
    const unsigned short* row = psi0 + (size_t)r * D_PAD;
    unsigned char* orow = u8 + (size_t)r * D_PAD;
    float s = 0.f;
    for (int c = lane; c < D_PAD / 8; c += 64) {
        int4 v = *(const int4*)(row + c * 8);
        const unsigned short* u = (const unsigned short*)&v;
        unsigned long long w = 0ull;
#pragma unroll
        for (int e = 0; e < 8; e++) {
            float f = bf2f(u[e]);
            s += f * f;
            w |= (unsigned long long)f2fp8(f) << (8 * e);
        }
        *(unsigned long long*)(orow + c * 8) = w;
    }
    s += __shfl_xor(s, 1); s += __shfl_xor(s, 2); s += __shfl_xor(s, 4);
    s += __shfl_xor(s, 8); s += __shfl_xor(s, 16); s += __shfl_xor(s, 32);
    if (lane == 0) rowsqP[r] = s;   // slot 0; slots 1..43 zeroed by init
}

// ---- MFMA GEMM (NT), all-fp8 operands, 64x64 tile, 64B K-step, 6-buf depth-5 ----
// MODE 0: u = (z8@c8)/128 + psi -> u8 (+ fused cost); MODE 1: fp8 kernel + RK4;
// MODE 2: cost quadratic form (descaled). T14 epilogue-input prefetch throughout.
struct GemmArgs {
    const unsigned char* A; const unsigned char* B;
    int lda, ldb, K;        // BYTES
    int gx;
    // MODE 0
    const unsigned short* psi16; unsigned char* u8; float* rowsqP;
    int do_cost;
    // MODE 0 (cost fusion) + MODE 2
    const float* cfp; float* cost;
    // MODE 1
    float* zcur; unsigned short* accb16; unsigned char* zt8; float* outp;
    int first, finish, tout; float alpha, h6;
};

template<int MODE>
__global__ __launch_bounds__(256) void mfma_gemm(GemmArgs g) {
    __shared__ __align__(16) unsigned char As[6][64][64];
    __shared__ __align__(16) unsigned char Bs[6][64][64];
    __shared__ float sclM[64], ahM[64], sclN[64], ahN[64];
    __shared__ float red4[4];
    const int nb = gridDim.x;
    const int lin = blockIdx.x;
    const int swz = (lin & 7) * (nb >> 3) + (lin >> 3);
    const int bx = swz % g.gx, by = swz / g.gx;
    const int bm = by * 64, bn = bx * 64;
    const int t = threadIdx.x;
    const int lane = t & 63, wv = t >> 6;
    const int wm = (wv >> 1) * 32, wn = (wv & 1) * 32;
    const int lr = lane & 15, lg = lane >> 4;
    const int srow = lane >> 2;
    const int gch = (lane & 3) ^ ((lane >> 3) & 3);

    if (MODE == 1) {
        if (t < 128) {
            int r = (t < 64) ? (bm + t) : (bn + (t - 64));
            float tot = 0.f;
#pragma unroll
            for (int c = 0; c < NPART; c++) tot += g.rowsqP[(size_t)c * N_TOT + r];
            float norm = sqrtf(tot + 1e-6f);
            float sg = 1.f / (1.f + __expf(-norm));
            float sc = sg / norm;
            float a = 0.5f * tot * sc * sc;
            if (t < 64) { sclM[t] = sc; ahM[t] = a; }
            else        { sclN[t - 64] = sc; ahN[t - 64] = a; }
        }
    }

    // ---- T14: early epilogue-input loads (independent of MFMA results) ----
    const bool docost = (MODE == 0) && g.do_cost && (bm < S_ANCH);
    unsigned short psi_r[2][4][2];
    float cfp_r[2][4][2];
    float zc_r[2][4][2];
    unsigned short ab_r[2][4][2];
    if (MODE == 0) {
#pragma unroll
        for (int i = 0; i < 2; i++)
#pragma unroll
            for (int reg = 0; reg < 4; reg++) {
                int m = bm + wm + i * 16 + lg * 4 + reg;
#pragma unroll
                for (int j = 0; j < 2; j++) {
                    int n = bn + wn + j * 16 + lr;
                    psi_r[i][reg][j] = g.psi16[(size_t)m * D_PAD + n];
                    if (docost)
                        cfp_r[i][reg][j] = (n < D_DIM) ? g.cfp[(size_t)m * D_DIM + n] : 0.f;
                }
            }
    } else if (MODE == 1) {
#pragma unroll
        for (int i = 0; i < 2; i++)
#pragma unroll
            for (int reg = 0; reg < 4; reg++) {
                int m = bm + wm + i * 16 + lg * 4 + reg;
#pragma unroll
                for (int j = 0; j < 2; j++) {
                    int n = bn + wn + j * 16 + lr;
                    size_t idx = (size_t)m * S_ANCH + n;
                    zc_r[i][reg][j] = g.zcur[idx];
                    ab_r[i][reg][j] = g.accb16[idx];
                }
            }
    }
    __builtin_amdgcn_sched_barrier(0);   // pin early loads before staging

    f32x4 acc[2][2];
#pragma unroll
    for (int i = 0; i < 2; i++)
#pragma unroll
        for (int j = 0; j < 2; j++) acc[i][j] = (f32x4){0.f, 0.f, 0.f, 0.f};

    const unsigned char* Abase = g.A + (size_t)(bm + wv * 16 + srow) * g.lda + gch * 16;
    const unsigned char* Bbase = g.B + (size_t)(bn + wv * 16 + srow) * g.ldb + gch * 16;

    auto STAGE = [&](int k) {
        int buf = k % 6;
        stage16(Abase + (k << 6), &As[buf][wv * 16][0]);
        stage16(Bbase + (k << 6), &Bs[buf][wv * 16][0]);
    };
    auto COMPUTE = [&](int k) {
        int buf = k % 6;
#pragma unroll
        for (int ks = 0; ks < 2; ks++) {
            int ch = ((ks << 1) + (lg >> 1)) ^ ((lr >> 1) & 3);
            int off = ch * 16 + (lg & 1) * 8;
            long a0 = *(const long*)&As[buf][wm + lr][off];
            long a1 = *(const long*)&As[buf][wm + 16 + lr][off];
            long b0 = *(const long*)&Bs[buf][wn + lr][off];
            long b1 = *(const long*)&Bs[buf][wn + 16 + lr][off];
            acc[0][0] = __builtin_amdgcn_mfma_f32_16x16x32_fp8_fp8(a0, b0, acc[0][0], 0, 0, 0);
            acc[0][1] = __builtin_amdgcn_mfma_f32_16x16x32_fp8_fp8(a0, b1, acc[0][1], 0, 0, 0);
            acc[1][0] = __builtin_amdgcn_mfma_f32_16x16x32_fp8_fp8(a1, b0, acc[1][0], 0, 0, 0);
            acc[1][1] = __builtin_amdgcn_mfma_f32_16x16x32_fp8_fp8(a1, b1, acc[1][1], 0, 0, 0);
        }
    };

    const int nt = g.K >> 6;   // 16 (K=1024B) or 22 (K=1408B); always > 6
    STAGE(0); STAGE(1); STAGE(2); STAGE(3); STAGE(4);
    for (int k = 0; k < nt - 5; ++k) {
        asm volatile("s_waitcnt vmcnt(8)" ::: "memory");
        __builtin_amdgcn_s_barrier();
        __builtin_amdgcn_sched_barrier(0);
        STAGE(k + 5);
        COMPUTE(k);
    }
    asm volatile("s_waitcnt vmcnt(8)" ::: "memory");
    __builtin_amdgcn_s_barrier(); __builtin_amdgcn_sched_barrier(0);
    COMPUTE(nt - 5);
    asm volatile("s_waitcnt vmcnt(6)" ::: "memory");
    __builtin_amdgcn_s_barrier(); __builtin_amdgcn_sched_barrier(0);
    COMPUTE(nt - 4);
    asm volatile("s_waitcnt vmcnt(4)" ::: "memory");
    __builtin_amdgcn_s_barrier(); __builtin_amdgcn_sched_barrier(0);
    COMPUTE(nt - 3);
    asm volatile("s_waitcnt vmcnt(2)" ::: "memory");
    __builtin_amdgcn_s_barrier(); __builtin_amdgcn_sched_barrier(0);
    COMPUTE(nt - 2);
    asm volatile("s_waitcnt vmcnt(0)" ::: "memory");
    __builtin_amdgcn_s_barrier(); __builtin_amdgcn_sched_barrier(0);
    COMPUTE(nt - 1);

    // ---------------- epilogues (inputs already in registers) ----------------
    if (MODE == 0) {
        float cst = 0.f;
#pragma unroll
        for (int i = 0; i < 2; i++) {
#pragma unroll
            for (int reg = 0; reg < 4; reg++) {
                int m = bm + wm + i * 16 + lg * 4 + reg;
                float sq = 0.f;
#pragma unroll
                for (int j = 0; j < 2; j++) {
                    int n = bn + wn + j * 16 + lr;
                    float v = acc[i][j][reg] * CINV;   // descale c*128
                    bool nok = n < D_DIM;
                    if (docost) cst += v * cfp_r[i][reg][j];
                    if (nok) v += bf2f(psi_r[i][reg][j]);
                    else v = 0.f;
                    g.u8[(size_t)m * D_PAD + n] = f2fp8(v);
                    sq += v * v;
                }
                sq += __shfl_xor(sq, 1);
                sq += __shfl_xor(sq, 2);
                sq += __shfl_xor(sq, 4);
                sq += __shfl_xor(sq, 8);
                if (lr == 0)
                    g.rowsqP[(size_t)(bx * 2 + (wn >> 5)) * N_TOT + m] = sq;
            }
        }
        if (docost) {
            cst += __shfl_xor(cst, 1); cst += __shfl_xor(cst, 2);
            cst += __shfl_xor(cst, 4); cst += __shfl_xor(cst, 8);
            cst += __shfl_xor(cst, 16); cst += __shfl_xor(cst, 32);
            if (lane == 0) red4[wv] = cst;
            __syncthreads();
            if (t == 0) atomicAdd(g.cost, red4[0] + red4[1] + red4[2] + red4[3]);
        }
    } else if (MODE == 1) {
        __syncthreads();  // stats visibility
#pragma unroll
        for (int i = 0; i < 2; i++) {
#pragma unroll
            for (int reg = 0; reg < 4; reg++) {
                int mi = wm + i * 16 + lg * 4 + reg;
                int m = bm + mi;
                float sm = sclM[mi], am = ahM[mi];
#pragma unroll
                for (int j = 0; j < 2; j++) {
                    int ni = wn + j * 16 + lr;
                    int n = bn + ni;
                    float uv = acc[i][j][reg] * sm * sclN[ni];
                    float kv = __expf(uv - am - ahN[ni]) * uv;
                    size_t idx = (size_t)m * S_ANCH + n;
                    if (!g.finish) {
                        float ab = g.first ? kv : (bf2f(ab_r[i][reg][j]) + 2.0f * kv);
                        g.accb16[idx] = f2bf(ab);
                        float zt = zc_r[i][reg][j] + g.alpha * kv;
                        g.zt8[idx] = f2fp8(zt);
                    } else {
                        float z = zc_r[i][reg][j] + g.h6 * (bf2f(ab_r[i][reg][j]) + kv);
                        g.zcur[idx] = z;
                        g.zt8[idx] = f2fp8(z);
                        if (m >= S_ANCH)
                            g.outp[(size_t)(m - S_ANCH) * (F_NUM * S_ANCH)
                                   + (size_t)g.tout * S_ANCH + n] = z;
                    }
                }
            }
        }
    } else {
        float s = 0.f;
#pragma unroll
        for (int i = 0; i < 2; i++)
#pragma unroll
            for (int reg = 0; reg < 4; reg++) {
                int m = bm + wm + i * 16 + lg * 4 + reg;
#pragma unroll
                for (int j = 0; j < 2; j++) {
                    int n = bn + wn + j * 16 + lr;
                    if (n < D_DIM)
                        s += acc[i][j][reg] * CINV * g.cfp[(size_t)m * D_DIM + n];
                }
            }
        s += __shfl_xor(s, 1); s += __shfl_xor(s, 2); s += __shfl_xor(s, 4);
        s += __shfl_xor(s, 8); s += __shfl_xor(s, 16); s += __shfl_xor(s, 32);
        if (lane == 0) red4[wv] = s;
        __syncthreads();
        if (t == 0) atomicAdd(g.cost, red4[0] + red4[1] + red4[2] + red4[3]);
    }
}

// ---------------- final: add conv_w/b square norm ----------------
__global__ __launch_bounds__(256) void final_kernel(const float* __restrict__ cw,
                                                    const float* __restrict__ cb,
                                                    const float* __restrict__ cost,
                                                    float* __restrict__ out) {
    float s = 0.f;
    for (int i = threadIdx.x; i < 720; i += 256) s += cw[i] * cw[i];
    for (int i = threadIdx.x; i < 80; i += 256) s += cb[i] * cb[i];
    for (int o = 32; o > 0; o >>= 1) s += __shfl_down(s, o);
    __shared__ float red[4];
    if ((threadIdx.x & 63) == 0) red[threadIdx.x >> 6] = s;
    __syncthreads();
    if (threadIdx.x == 0) out[0] = red[0] + red[1] + red[2] + red[3] + cost[0] / 10.0f;
}

// ---------------- host ----------------
extern "C" void kernel_launch(void* const* d_in, const int* in_sizes, int n_in,
                              void* d_out, int out_size, void* d_ws, size_t ws_size,
                              hipStream_t stream) {
    (void)in_sizes; (void)n_in; (void)out_size; (void)ws_size;
    const float* data   = (const float*)d_in[0];
    const float* inputs = (const float*)d_in[1];
    const float* conv_w = (const float*)d_in[2];
    const float* conv_b = (const float*)d_in[3];
    const float* c_s    = (const float*)d_in[4];
    float* out = (float*)d_out;

    char* ws = (char*)d_ws;
    size_t off = 0;
    auto alloc = [&](size_t bytes) {
        char* p = ws + off; off += (bytes + 255) & ~(size_t)255; return p;
    };
    unsigned char*  c8_all  = (unsigned char*)alloc((size_t)N_TV * CST);        // 27.4 MB
    float*          cfp_all = (float*)alloc((size_t)9 * SD * 4);                // 49.8 MB
    unsigned short* psi_all = (unsigned short*)alloc((size_t)N_TV * PSIP * 2);  // 164.4 MB
    unsigned char*  u8      = (unsigned char*)alloc(PSIP);                      // 4.3 MB
    float*          z_cur   = (float*)alloc(NS * 4);
    unsigned char*  z8      = (unsigned char*)alloc(NS);
    unsigned char*  zt8     = (unsigned char*)alloc(NS);
    unsigned short* accb16  = (unsigned short*)alloc(NS * 2);
    float*          rowsqP  = (float*)alloc((size_t)NPART * N_TOT * 4);
    float*          cost    = (float*)alloc(64);

    const double TAU_D = 6.2831853071795864769;
    float ts[F_NUM];
    for (int i = 0; i < F_NUM; i++) ts[i] = (float)((double)i / 9.0);
    W190 Wall;
    for (int j = 0; j < N_TV; j++) {
        float tt;
        if ((j & 1) == 0) tt = ts[j >> 1];
        else {
            int i = j >> 1;
            float h = ts[i + 1] - ts[i];
            tt = ts[i] + 0.5f * h;
        }
        for (int f = 0; f < F_NUM; f++) {
            float coeff = (float)(TAU_D * f);
            float targ = tt * coeff;
            Wall.w[j][f] = (float)cos((double)targ);
        }
    }

    init_kernel<<<2048, 256, 0, stream>>>(z_cur, z8, cost, rowsqP, psi_all, out);
    c_all_kernel<<<dim3(22, 32), 256, 0, stream>>>(c_s, c8_all, cfp_all, Wall);
    const int conv_blocks = (int)(((size_t)N_TOT * 8 * 169 + 255) / 256);
    conv_psi_all_kernel<<<conv_blocks, 256, 0, stream>>>(data, inputs, conv_w, conv_b,
                                                         psi_all, Wall);

    GemmArgs g0 = {}; // GEMM1 (fp8): u = (z8@c8)/128 + psi (+ fused cost at e=0) -> u8
    g0.lda = S_ANCH; g0.ldb = S_ANCH; g0.K = S_ANCH; g0.gx = 22;
    g0.u8 = u8; g0.rowsqP = rowsqP; g0.cost = cost;
    GemmArgs g1 = {}; // GEMM2 (fp8): kernel + RK4 bookkeeping
    g1.A = u8; g1.B = u8; g1.lda = D_PAD; g1.ldb = D_PAD; g1.K = D_PAD; g1.gx = 16;
    g1.zcur = z_cur; g1.accb16 = accb16; g1.rowsqP = rowsqP;
    GemmArgs g2 = {}; // final cost quadratic form (fp8, t_9)
    g2.A = z8; g2.B = c8_all + (size_t)18 * CST;
    g2.lda = S_ANCH; g2.ldb = S_ANCH; g2.K = S_ANCH; g2.gx = 22;
    g2.cfp = cfp_all + (size_t)8 * SD; g2.cost = cost;

    for (int i = 0; i < 9; i++) {
        float h = ts[i + 1] - ts[i];
        int js[4] = {2 * i, 2 * i + 1, 2 * i + 1, 2 * i + 2};
        float alphas[3] = {0.5f * h, 0.5f * h, h};
        for (int e = 0; e < 4; e++) {
            int j = js[e];
            const bool shortcut = (i == 0 && e == 0);   // z == 0 -> u == psi
            if (shortcut) {
                rowsq_psi_kernel<<<N_TOT / 4, 256, 0, stream>>>(psi_all, rowsqP, u8);
            } else {
                g0.A = (e == 0) ? z8 : zt8;
                g0.B = c8_all + (size_t)j * CST;
                g0.psi16 = psi_all + (size_t)j * PSIP;
                g0.do_cost = (e == 0 && i >= 1) ? 1 : 0;
                g0.cfp = (i >= 1) ? (cfp_all + (size_t)(i - 1) * SD) : cfp_all;
                mfma_gemm<0><<<22 * 48, 256, 0, stream>>>(g0);
            }
            g1.first = (e == 0); g1.finish = (e == 3);
            g1.alpha = (e < 3) ? alphas[e] : 0.f;
            g1.h6 = h / 6.0f; g1.tout = i + 1;
            g1.zt8 = (e < 3) ? zt8 : z8;
            g1.outp = out;
            mfma_gemm<1><<<16 * 48, 256, 0, stream>>>(g1);
        }
    }
    // cost contribution at t_9 (z8 holds z_{t9})
    mfma_gemm<2><<<22 * 16, 256, 0, stream>>>(g2);

    final_kernel<<<1, 256, 0, stream>>>(conv_w, conv_b, cost, out + OUT_Z);
}

// Round 19
// 1653.154 us; speedup vs baseline: 3.4416x; 1.0130x over previous
//
#include <hip/hip_runtime.h>
#include <hip/hip_fp8.h>
#include <math.h>

#define S_ANCH 1024
#define B_QRY  2048
#define N_TOT  3072
#define D_DIM  1352
#define D_PAD  1408   // padded D: u8/psi stride (elements), c8 rows
#define F_NUM  10
#define N_TV   19
#define NPART  44     // 22 n-tiles * 2 wave-halves in GEMM1
#define CSCALE 128.0f
#define CINV   (1.0f / 128.0f)

static const size_t SD    = (size_t)S_ANCH * D_DIM;
static const size_t NS    = (size_t)N_TOT * S_ANCH;
static const size_t CST   = (size_t)D_PAD * S_ANCH;   // one c8 plane (bytes)
static const size_t PSIP  = (size_t)N_TOT * D_PAD;    // one psi plane (bytes, fp8)
static const size_t OUT_Z = (size_t)B_QRY * F_NUM * S_ANCH;

typedef __attribute__((ext_vector_type(4))) float f32x4;

struct W190 { float w[N_TV][F_NUM]; };

__device__ inline unsigned short f2bf(float x) {
    unsigned int u = __builtin_bit_cast(unsigned int, x);
    unsigned int r = (u + 0x7FFFu + ((u >> 16) & 1u)) >> 16;
    return (unsigned short)r;
}
__device__ inline float bf2f(unsigned short v) {
    unsigned int u = ((unsigned int)v) << 16;
    return __builtin_bit_cast(float, u);
}
__device__ inline unsigned char f2fp8(float x) {
    __hip_fp8_e4m3 q(x);            // OCP e4m3fn on gfx950, saturating
    return (unsigned char)q.__x;
}
__device__ inline float fp82f(unsigned char b) {
    __hip_fp8_e4m3 q; q.__x = b;
    return (float)q;
}

__device__ __forceinline__ void stage16(const unsigned char* gp, unsigned char* lp) {
    __builtin_amdgcn_global_load_lds(
        (const __attribute__((address_space(1))) unsigned int*)(const void*)gp,
        (__attribute__((address_space(3))) unsigned int*)(void*)lp, 16, 0, 0);
}

// ------- init: zero z, z8, cost, rowsqP, psi-plane0 pad, t=0 out slice -------
__global__ __launch_bounds__(256) void init_kernel(float* __restrict__ z,
                                                   unsigned char* __restrict__ z8,
                                                   float* __restrict__ cost,
                                                   float* __restrict__ rowsqP,
                                                   unsigned char* __restrict__ psi0,
                                                   float* __restrict__ out) {
    size_t idx = (size_t)blockIdx.x * blockDim.x + threadIdx.x;
    size_t stride = (size_t)gridDim.x * blockDim.x;
    for (size_t i = idx; i < NS; i += stride) { z[i] = 0.f; z8[i] = 0; }
    const size_t NO = (size_t)B_QRY * S_ANCH;
    for (size_t i = idx; i < NO; i += stride) {
        size_t b = i >> 10, s = i & 1023;
        out[b * (size_t)(F_NUM * S_ANCH) + s] = 0.f;
    }
    const size_t NR = (size_t)NPART * N_TOT;
    for (size_t i = idx; i < NR; i += stride) rowsqP[i] = 0.f;
    const size_t NPAD = (size_t)N_TOT * (D_PAD - D_DIM);
    for (size_t i = idx; i < NPAD; i += stride) {
        size_t n = i / (D_PAD - D_DIM), c = i % (D_PAD - D_DIM);
        psi0[n * D_PAD + D_DIM + c] = 0;
    }
    if (idx == 0) cost[0] = 0.f;
}

// ------- ALL c_t planes in one pass: fp8(c*128) transposed + fp32 cost planes -------
__global__ __launch_bounds__(256) void c_all_kernel(const float* __restrict__ cs,
                                                    unsigned char* __restrict__ c8,
                                                    float* __restrict__ cfp, W190 W) {
    __shared__ float tile[32][65];
    int d0 = blockIdx.x * 64, s0 = blockIdx.y * 32;
    int t = threadIdx.x;
    int d_l = t & 63, s_base = t >> 6;
    int d = d0 + d_l;
    bool dok = (d < D_DIM);
    float creg[8][F_NUM];
#pragma unroll
    for (int it = 0; it < 8; it++) {
        int s = s0 + s_base + it * 4;
        const float* p = cs + ((size_t)s * D_DIM + d) * F_NUM;
#pragma unroll
        for (int f = 0; f < F_NUM; f++) creg[it][f] = dok ? p[f] : 0.f;
    }
    for (int j = 0; j < N_TV; j++) {
        float v[8];
#pragma unroll
        for (int it = 0; it < 8; it++) {
            float s = 0.f;
#pragma unroll
            for (int f = 0; f < F_NUM; f++) s += creg[it][f] * W.w[j][f];
            v[it] = s;
            tile[s_base + it * 4][d_l] = s;
        }
        if ((j & 1) == 0 && j >= 2 && dok) {
            int gi = (j >> 1) - 1;
#pragma unroll
            for (int it = 0; it < 8; it++)
                cfp[(size_t)gi * SD + (size_t)(s0 + s_base + it * 4) * D_DIM + d] = v[it];
        }
        __syncthreads();
        int s_l = t & 31, dr = t >> 5;
#pragma unroll
        for (int p8 = 0; p8 < 8; p8++) {
            int dd = dr + p8 * 8;
            c8[(size_t)j * CST + (size_t)(d0 + dd) * S_ANCH + s0 + s_l] =
                f2fp8(tile[s_l][dd] * CSCALE);
        }
        __syncthreads();
    }
}

// ---------------- ALL psi_t planes (fp8): conv once, 19 freq-dots ----------------
__global__ __launch_bounds__(256) void conv_psi_all_kernel(const float* __restrict__ data,
                                                           const float* __restrict__ inputs,
                                                           const float* __restrict__ cw,
                                                           const float* __restrict__ cb,
                                                           unsigned char* __restrict__ psi_all,
                                                           W190 W) {
    __shared__ float wsh[720];
    __shared__ float bsh[80];
    for (int i = threadIdx.x; i < 720; i += 256) wsh[i] = cw[i];
    for (int i = threadIdx.x; i < 80; i += 256) bsh[i] = cb[i];
    __syncthreads();
    size_t idx = (size_t)blockIdx.x * 256 + threadIdx.x;
    if (idx >= (size_t)N_TOT * 8 * 169) return;
    int pos = (int)(idx % 169);
    int rest = (int)(idx / 169);
    int c8 = rest & 7;
    int n = rest >> 3;
    int oi = pos / 13, oj = pos % 13;
    const float* x = (n < S_ANCH) ? (data + (size_t)n * 784)
                                  : (inputs + (size_t)(n - S_ANCH) * 784);
    float vin[9];
#pragma unroll
    for (int kh = 0; kh < 3; kh++)
#pragma unroll
        for (int kw = 0; kw < 3; kw++)
            vin[kh * 3 + kw] = x[(2 * oi + kh) * 28 + (2 * oj + kw)];
    float s[F_NUM];
#pragma unroll
    for (int f = 0; f < F_NUM; f++) {
        int co = f * 8 + c8;
        float acc = bsh[co];
#pragma unroll
        for (int t = 0; t < 9; t++) acc += vin[t] * wsh[co * 9 + t];
        s[f] = acc;
    }
    size_t base = (size_t)n * D_PAD + c8 * 169 + pos;
#pragma unroll
    for (int j = 0; j < N_TV; j++) {
        float p = 0.f;
#pragma unroll
        for (int f = 0; f < F_NUM; f++) p += s[f] * W.w[j][f];
        psi_all[(size_t)j * PSIP + base] = f2fp8(p);
    }
}

// -- rowsq of psi plane 0 (fp8) for the t=0 shortcut (u == psi, read in place) --
__global__ __launch_bounds__(256) void rowsq_psi_kernel(const unsigned char* __restrict__ psi0,
                                                        float* __restrict__ rowsqP) {
    int wv = threadIdx.x >> 6, lane = threadIdx.x & 63;
    int r = blockIdx.x * 4 + wv;
    const unsigned char* row = psi0 + (size_t)r * D_PAD;
    float s = 0.f;
    for (int c = lane; c < D_PAD / 8; c += 64) {
        unsigned long long w = *(const unsigned long long*)(row + c * 8);
#pragma unroll
        for (int e = 0; e < 8; e++) {
            float f = fp82f((unsigned char)(w >> (8 * e)));
            s += f * f;
        }
    }
    s += __shfl_xor(s, 1); s += __shfl_xor(s, 2); s += __shfl_xor(s, 4);
    s += __shfl_xor(s, 8); s += __shfl_xor(s, 16); s += __shfl_xor(s, 32);
    if (lane == 0) rowsqP[r] = s;   // slot 0; slots 1..43 zeroed by init
}

// ---- MFMA GEMM (NT), all-fp8, 64x64 tile, 64B K-step, 4-buf depth-3 vmcnt(4) ----
struct GemmArgs {
    const unsigned char* A; const unsigned char* B;
    int lda, ldb, K;        // BYTES
    int gx;
    // MODE 0
    const unsigned char* psi8; unsigned char* u8; float* rowsqP;
    int do_cost;
    // MODE 0 (cost fusion) + MODE 2
    const float* cfp; float* cost;
    // MODE 1
    float* zcur; unsigned short* accb16; unsigned char* zt8; float* outp;
    int first, finish, tout; float alpha, h6;
};

template<int MODE>
__global__ __launch_bounds__(256) void mfma_gemm(GemmArgs g) {
    __shared__ __align__(16) unsigned char As[4][64][64];
    __shared__ __align__(16) unsigned char Bs[4][64][64];
    __shared__ float sclM[64], ahM[64], sclN[64], ahN[64];
    __shared__ float red4[4];
    const int nb = gridDim.x;
    const int lin = blockIdx.x;
    const int swz = (lin & 7) * (nb >> 3) + (lin >> 3);
    const int bx = swz % g.gx, by = swz / g.gx;
    const int bm = by * 64, bn = bx * 64;
    const int t = threadIdx.x;
    const int lane = t & 63, wv = t >> 6;
    const int wm = (wv >> 1) * 32, wn = (wv & 1) * 32;
    const int lr = lane & 15, lg = lane >> 4;
    const int srow = lane >> 2;
    const int gch = (lane & 3) ^ ((lane >> 3) & 3);

    if (MODE == 1) {
        if (t < 128) {
            int r = (t < 64) ? (bm + t) : (bn + (t - 64));
            float tot = 0.f;
#pragma unroll
            for (int c = 0; c < NPART; c++) tot += g.rowsqP[(size_t)c * N_TOT + r];
            float norm = sqrtf(tot + 1e-6f);
            float sg = 1.f / (1.f + __expf(-norm));
            float sc = sg / norm;
            float a = 0.5f * tot * sc * sc;
            if (t < 64) { sclM[t] = sc; ahM[t] = a; }
            else        { sclN[t - 64] = sc; ahN[t - 64] = a; }
        }
    }

    // ---- T14: early epilogue-input loads (independent of MFMA results) ----
    const bool docost = (MODE == 0) && g.do_cost && (bm < S_ANCH);
    unsigned char psi_r[2][4][2];
    float cfp_r[2][4][2];
    float zc_r[2][4][2];
    unsigned short ab_r[2][4][2];
    if (MODE == 0) {
#pragma unroll
        for (int i = 0; i < 2; i++)
#pragma unroll
            for (int reg = 0; reg < 4; reg++) {
                int m = bm + wm + i * 16 + lg * 4 + reg;
#pragma unroll
                for (int j = 0; j < 2; j++) {
                    int n = bn + wn + j * 16 + lr;
                    psi_r[i][reg][j] = g.psi8[(size_t)m * D_PAD + n];
                    if (docost)
                        cfp_r[i][reg][j] = (n < D_DIM) ? g.cfp[(size_t)m * D_DIM + n] : 0.f;
                }
            }
    } else if (MODE == 1) {
#pragma unroll
        for (int i = 0; i < 2; i++)
#pragma unroll
            for (int reg = 0; reg < 4; reg++) {
                int m = bm + wm + i * 16 + lg * 4 + reg;
#pragma unroll
                for (int j = 0; j < 2; j++) {
                    int n = bn + wn + j * 16 + lr;
                    size_t idx = (size_t)m * S_ANCH + n;
                    zc_r[i][reg][j] = g.zcur[idx];
                    ab_r[i][reg][j] = g.accb16[idx];
                }
            }
    }
    __builtin_amdgcn_sched_barrier(0);   // pin early loads before staging

    f32x4 acc[2][2];
#pragma unroll
    for (int i = 0; i < 2; i++)
#pragma unroll
        for (int j = 0; j < 2; j++) acc[i][j] = (f32x4){0.f, 0.f, 0.f, 0.f};

    const unsigned char* Abase = g.A + (size_t)(bm + wv * 16 + srow) * g.lda + gch * 16;
    const unsigned char* Bbase = g.B + (size_t)(bn + wv * 16 + srow) * g.ldb + gch * 16;

    auto STAGE = [&](int k) {
        int buf = k & 3;
        stage16(Abase + (k << 6), &As[buf][wv * 16][0]);
        stage16(Bbase + (k << 6), &Bs[buf][wv * 16][0]);
    };
    auto COMPUTE = [&](int k) {
        int buf = k & 3;
#pragma unroll
        for (int ks = 0; ks < 2; ks++) {
            int ch = ((ks << 1) + (lg >> 1)) ^ ((lr >> 1) & 3);
            int off = ch * 16 + (lg & 1) * 8;
            long a0 = *(const long*)&As[buf][wm + lr][off];
            long a1 = *(const long*)&As[buf][wm + 16 + lr][off];
            long b0 = *(const long*)&Bs[buf][wn + lr][off];
            long b1 = *(const long*)&Bs[buf][wn + 16 + lr][off];
            acc[0][0] = __builtin_amdgcn_mfma_f32_16x16x32_fp8_fp8(a0, b0, acc[0][0], 0, 0, 0);
            acc[0][1] = __builtin_amdgcn_mfma_f32_16x16x32_fp8_fp8(a0, b1, acc[0][1], 0, 0, 0);
            acc[1][0] = __builtin_amdgcn_mfma_f32_16x16x32_fp8_fp8(a1, b0, acc[1][0], 0, 0, 0);
            acc[1][1] = __builtin_amdgcn_mfma_f32_16x16x32_fp8_fp8(a1, b1, acc[1][1], 0, 0, 0);
        }
    };

    const int nt = g.K >> 6;   // 16 (K=1024B) or 22 (K=1408B)
    STAGE(0); STAGE(1); STAGE(2);
    for (int k = 0; k < nt - 3; ++k) {
        asm volatile("s_waitcnt vmcnt(4)" ::: "memory");
        __builtin_amdgcn_s_barrier();
        __builtin_amdgcn_sched_barrier(0);
        STAGE(k + 3);
        COMPUTE(k);
    }
    asm volatile("s_waitcnt vmcnt(4)" ::: "memory");
    __builtin_amdgcn_s_barrier(); __builtin_amdgcn_sched_barrier(0);
    COMPUTE(nt - 3);
    asm volatile("s_waitcnt vmcnt(2)" ::: "memory");
    __builtin_amdgcn_s_barrier(); __builtin_amdgcn_sched_barrier(0);
    COMPUTE(nt - 2);
    asm volatile("s_waitcnt vmcnt(0)" ::: "memory");
    __builtin_amdgcn_s_barrier(); __builtin_amdgcn_sched_barrier(0);
    COMPUTE(nt - 1);

    // ---------------- epilogues (inputs already in registers) ----------------
    if (MODE == 0) {
        float cst = 0.f;
#pragma unroll
        for (int i = 0; i < 2; i++) {
#pragma unroll
            for (int reg = 0; reg < 4; reg++) {
                int m = bm + wm + i * 16 + lg * 4 + reg;
                float sq = 0.f;
#pragma unroll
                for (int j = 0; j < 2; j++) {
                    int n = bn + wn + j * 16 + lr;
                    float v = acc[i][j][reg] * CINV;   // descale c*128
                    bool nok = n < D_DIM;
                    if (docost) cst += v * cfp_r[i][reg][j];
                    if (nok) v += fp82f(psi_r[i][reg][j]);
                    else v = 0.f;
                    g.u8[(size_t)m * D_PAD + n] = f2fp8(v);
                    sq += v * v;
                }
                sq += __shfl_xor(sq, 1);
                sq += __shfl_xor(sq, 2);
                sq += __shfl_xor(sq, 4);
                sq += __shfl_xor(sq, 8);
                if (lr == 0)
                    g.rowsqP[(size_t)(bx * 2 + (wn >> 5)) * N_TOT + m] = sq;
            }
        }
        if (docost) {
            cst += __shfl_xor(cst, 1); cst += __shfl_xor(cst, 2);
            cst += __shfl_xor(cst, 4); cst += __shfl_xor(cst, 8);
            cst += __shfl_xor(cst, 16); cst += __shfl_xor(cst, 32);
            if (lane == 0) red4[wv] = cst;
            __syncthreads();
            if (t == 0) atomicAdd(g.cost, red4[0] + red4[1] + red4[2] + red4[3]);
        }
    } else if (MODE == 1) {
        __syncthreads();  // stats visibility
#pragma unroll
        for (int i = 0; i < 2; i++) {
#pragma unroll
            for (int reg = 0; reg < 4; reg++) {
                int mi = wm + i * 16 + lg * 4 + reg;
                int m = bm + mi;
                float sm = sclM[mi], am = ahM[mi];
#pragma unroll
                for (int j = 0; j < 2; j++) {
                    int ni = wn + j * 16 + lr;
                    int n = bn + ni;
                    float uv = acc[i][j][reg] * sm * sclN[ni];
                    float kv = __expf(uv - am - ahN[ni]) * uv;
                    size_t idx = (size_t)m * S_ANCH + n;
                    if (!g.finish) {
                        float ab = g.first ? kv : (bf2f(ab_r[i][reg][j]) + 2.0f * kv);
                        g.accb16[idx] = f2bf(ab);
                        float zt = zc_r[i][reg][j] + g.alpha * kv;
                        g.zt8[idx] = f2fp8(zt);
                    } else {
                        float z = zc_r[i][reg][j] + g.h6 * (bf2f(ab_r[i][reg][j]) + kv);
                        g.zcur[idx] = z;
                        g.zt8[idx] = f2fp8(z);
                        if (m >= S_ANCH)
                            g.outp[(size_t)(m - S_ANCH) * (F_NUM * S_ANCH)
                                   + (size_t)g.tout * S_ANCH + n] = z;
                    }
                }
            }
        }
    } else {
        float s = 0.f;
#pragma unroll
        for (int i = 0; i < 2; i++)
#pragma unroll
            for (int reg = 0; reg < 4; reg++) {
                int m = bm + wm + i * 16 + lg * 4 + reg;
#pragma unroll
                for (int j = 0; j < 2; j++) {
                    int n = bn + wn + j * 16 + lr;
                    if (n < D_DIM)
                        s += acc[i][j][reg] * CINV * g.cfp[(size_t)m * D_DIM + n];
                }
            }
        s += __shfl_xor(s, 1); s += __shfl_xor(s, 2); s += __shfl_xor(s, 4);
        s += __shfl_xor(s, 8); s += __shfl_xor(s, 16); s += __shfl_xor(s, 32);
        if (lane == 0) red4[wv] = s;
        __syncthreads();
        if (t == 0) atomicAdd(g.cost, red4[0] + red4[1] + red4[2] + red4[3]);
    }
}

// ---------------- final: add conv_w/b square norm ----------------
__global__ __launch_bounds__(256) void final_kernel(const float* __restrict__ cw,
                                                    const float* __restrict__ cb,
                                                    const float* __restrict__ cost,
                                                    float* __restrict__ out) {
    float s = 0.f;
    for (int i = threadIdx.x; i < 720; i += 256) s += cw[i] * cw[i];
    for (int i = threadIdx.x; i < 80; i += 256) s += cb[i] * cb[i];
    for (int o = 32; o > 0; o >>= 1) s += __shfl_down(s, o);
    __shared__ float red[4];
    if ((threadIdx.x & 63) == 0) red[threadIdx.x >> 6] = s;
    __syncthreads();
    if (threadIdx.x == 0) out[0] = red[0] + red[1] + red[2] + red[3] + cost[0] / 10.0f;
}

// ---------------- host ----------------
extern "C" void kernel_launch(void* const* d_in, const int* in_sizes, int n_in,
                              void* d_out, int out_size, void* d_ws, size_t ws_size,
                              hipStream_t stream) {
    (void)in_sizes; (void)n_in; (void)out_size; (void)ws_size;
    const float* data   = (const float*)d_in[0];
    const float* inputs = (const float*)d_in[1];
    const float* conv_w = (const float*)d_in[2];
    const float* conv_b = (const float*)d_in[3];
    const float* c_s    = (const float*)d_in[4];
    float* out = (float*)d_out;

    char* ws = (char*)d_ws;
    size_t off = 0;
    auto alloc = [&](size_t bytes) {
        char* p = ws + off; off += (bytes + 255) & ~(size_t)255; return p;
    };
    unsigned char*  c8_all  = (unsigned char*)alloc((size_t)N_TV * CST);       // 27.4 MB
    float*          cfp_all = (float*)alloc((size_t)9 * SD * 4);               // 49.8 MB
    unsigned char*  psi_all = (unsigned char*)alloc((size_t)N_TV * PSIP);      // 82.2 MB
    unsigned char*  u8      = (unsigned char*)alloc(PSIP);                     // 4.3 MB
    float*          z_cur   = (float*)alloc(NS * 4);
    unsigned char*  z8      = (unsigned char*)alloc(NS);
    unsigned char*  zt8     = (unsigned char*)alloc(NS);
    unsigned short* accb16  = (unsigned short*)alloc(NS * 2);
    float*          rowsqP  = (float*)alloc((size_t)NPART * N_TOT * 4);
    float*          cost    = (float*)alloc(64);

    const double TAU_D = 6.2831853071795864769;
    float ts[F_NUM];
    for (int i = 0; i < F_NUM; i++) ts[i] = (float)((double)i / 9.0);
    W190 Wall;
    for (int j = 0; j < N_TV; j++) {
        float tt;
        if ((j & 1) == 0) tt = ts[j >> 1];
        else {
            int i = j >> 1;
            float h = ts[i + 1] - ts[i];
            tt = ts[i] + 0.5f * h;
        }
        for (int f = 0; f < F_NUM; f++) {
            float coeff = (float)(TAU_D * f);
            float targ = tt * coeff;
            Wall.w[j][f] = (float)cos((double)targ);
        }
    }

    init_kernel<<<2048, 256, 0, stream>>>(z_cur, z8, cost, rowsqP, psi_all, out);
    c_all_kernel<<<dim3(22, 32), 256, 0, stream>>>(c_s, c8_all, cfp_all, Wall);
    const int conv_blocks = (int)(((size_t)N_TOT * 8 * 169 + 255) / 256);
    conv_psi_all_kernel<<<conv_blocks, 256, 0, stream>>>(data, inputs, conv_w, conv_b,
                                                         psi_all, Wall);

    GemmArgs g0 = {}; // GEMM1 (fp8): u = (z8@c8)/128 + psi (+ fused cost at e=0) -> u8
    g0.lda = S_ANCH; g0.ldb = S_ANCH; g0.K = S_ANCH; g0.gx = 22;
    g0.u8 = u8; g0.rowsqP = rowsqP; g0.cost = cost;
    GemmArgs g1 = {}; // GEMM2 (fp8): kernel + RK4 bookkeeping
    g1.lda = D_PAD; g1.ldb = D_PAD; g1.K = D_PAD; g1.gx = 16;
    g1.zcur = z_cur; g1.accb16 = accb16; g1.rowsqP = rowsqP;
    GemmArgs g2 = {}; // final cost quadratic form (fp8, t_9)
    g2.A = z8; g2.B = c8_all + (size_t)18 * CST;
    g2.lda = S_ANCH; g2.ldb = S_ANCH; g2.K = S_ANCH; g2.gx = 22;
    g2.cfp = cfp_all + (size_t)8 * SD; g2.cost = cost;

    for (int i = 0; i < 9; i++) {
        float h = ts[i + 1] - ts[i];
        int js[4] = {2 * i, 2 * i + 1, 2 * i + 1, 2 * i + 2};
        float alphas[3] = {0.5f * h, 0.5f * h, h};
        for (int e = 0; e < 4; e++) {
            int j = js[e];
            const bool shortcut = (i == 0 && e == 0);   // z == 0 -> u == psi (plane 0)
            if (shortcut) {
                rowsq_psi_kernel<<<N_TOT / 4, 256, 0, stream>>>(psi_all, rowsqP);
            } else {
                g0.A = (e == 0) ? z8 : zt8;
                g0.B = c8_all + (size_t)j * CST;
                g0.psi8 = psi_all + (size_t)j * PSIP;
                g0.do_cost = (e == 0 && i >= 1) ? 1 : 0;
                g0.cfp = (i >= 1) ? (cfp_all + (size_t)(i - 1) * SD) : cfp_all;
                mfma_gemm<0><<<22 * 48, 256, 0, stream>>>(g0);
            }
            g1.A = shortcut ? psi_all : u8;
            g1.B = shortcut ? psi_all : u8;
            g1.first = (e == 0); g1.finish = (e == 3);
            g1.alpha = (e < 3) ? alphas[e] : 0.f;
            g1.h6 = h / 6.0f; g1.tout = i + 1;
            g1.zt8 = (e < 3) ? zt8 : z8;
            g1.outp = out;
            mfma_gemm<1><<<16 * 48, 256, 0, stream>>>(g1);
        }
    }
    // cost contribution at t_9 (z8 holds z_{t9})
    mfma_gemm<2><<<22 * 16, 256, 0, stream>>>(g2);

    final_kernel<<<1, 256, 0, stream>>>(conv_w, conv_b, cost, out + OUT_Z);
}